// Round 1
// baseline (848.296 us; speedup 1.0000x reference)
//
#include <hip/hip_runtime.h>

// Problem constants (match reference)
constexpr int N_  = 100000;   // nodes
constexpr int E_  = 1600000;  // edges
constexpr int B_  = 2048;     // pairs
constexpr int IN_ = 4;        // input one-hot dim
constexpr int H_  = 32;       // hidden dim
constexpr int L_  = 4;        // layers

// ---------------- Layer 0 node transform (K = IN = 4) ----------------
// Computes agg[n,h] = bias0[h] + sum_k x[n,k]*loop0[k,h]
//          xb[n,b,h] = sum_k x[n,k]*V0[b,k,h]
__global__ __launch_bounds__(256) void node0_kernel(
    const float* __restrict__ x, const float* __restrict__ V0,
    const float* __restrict__ loop0, const float* __restrict__ bias0,
    float* __restrict__ xb, float* __restrict__ agg)
{
    __shared__ float xrow[8][4];
    const int tid  = threadIdx.x;
    const int lane = tid & 31;
    const int nl   = tid >> 5;
    const int node = blockIdx.x * 8 + nl;
    const bool ok  = node < N_;
    if (ok && lane < IN_) xrow[nl][lane] = x[node * IN_ + lane];
    // each node-group (32 lanes) is wholly inside one wave: write->read is safe
    if (ok) {
        float aL = bias0[lane], a0 = 0.f, a1 = 0.f;
#pragma unroll
        for (int k = 0; k < IN_; ++k) {
            const float hk = xrow[nl][k];
            aL += hk * loop0[k * 32 + lane];
            a0 += hk * V0[k * 32 + lane];           // V0[0,k,:]
            a1 += hk * V0[128 + k * 32 + lane];     // V0[1,k,:]
        }
        agg[node * 32 + lane]     = aL;
        xb[node * 64 + lane]      = a0;
        xb[node * 64 + 32 + lane] = a1;
    }
}

// ---------------- Layers 1..3 node transform (K = H = 32) ----------------
__global__ __launch_bounds__(256) void node_kernel(
    const float* __restrict__ cs, int in_off,
    const float* __restrict__ V, const float* __restrict__ loopW,
    const float* __restrict__ bias,
    float* __restrict__ xb, float* __restrict__ agg)
{
    __shared__ float hrow[8][32];
    const int tid  = threadIdx.x;
    const int lane = tid & 31;
    const int nl   = tid >> 5;
    const int node = blockIdx.x * 8 + nl;
    const bool ok  = node < N_;
    if (ok) hrow[nl][lane] = cs[node * 128 + in_off + lane];
    if (ok) {
        float aL = bias[lane], a0 = 0.f, a1 = 0.f;
#pragma unroll
        for (int k = 0; k < 32; ++k) {
            const float hk = hrow[nl][k];
            aL += hk * loopW[k * 32 + lane];
            a0 += hk * V[k * 32 + lane];            // V[0,k,:]
            a1 += hk * V[1024 + k * 32 + lane];     // V[1,k,:]
        }
        agg[node * 32 + lane]     = aL;
        xb[node * 64 + lane]      = a0;
        xb[node * 64 + 32 + lane] = a1;
    }
}

// ---------------- Edge aggregation ----------------
// 32 lanes per edge (lane = h). m = c0*xb[src,0,h] + c1*xb[src,1,h]; atomicAdd agg[dst,h].
__global__ __launch_bounds__(256) void edge_kernel(
    const int* __restrict__ src, const int* __restrict__ dst,
    const int* __restrict__ etype, const float* __restrict__ comp,
    const float* __restrict__ xb, float* __restrict__ agg)
{
    const int tid = blockIdx.x * 256 + threadIdx.x;
    const int e = tid >> 5;
    const int h = tid & 31;
    if (e >= E_) return;
    const int s = src[e];
    const int d = dst[e];
    const int t = etype[e];
    const float c0 = comp[t * 2 + 0];
    const float c1 = comp[t * 2 + 1];
    const float m = c0 * xb[s * 64 + h] + c1 * xb[s * 64 + 32 + h];
    atomicAdd(&agg[d * 32 + h], m);
}

// ---------------- tanh + write to concat buffer ----------------
__global__ __launch_bounds__(256) void tanh_kernel(
    const float* __restrict__ agg, float* __restrict__ cs, int out_off)
{
    const int tid = blockIdx.x * 256 + threadIdx.x;
    if (tid >= N_ * 32) return;
    const int n = tid >> 5;
    const int h = tid & 31;
    cs[n * 128 + out_off + h] = tanhf(agg[tid]);
}

// ---------------- transpose w1 [128,256] -> w1t [256,128] ----------------
__global__ __launch_bounds__(256) void transpose_w1_kernel(
    const float* __restrict__ w1, float* __restrict__ w1t)
{
    const int idx = blockIdx.x * 256 + threadIdx.x;
    if (idx >= 128 * 256) return;
    const int j = idx >> 8;     // row in w1 (hidden unit)
    const int k = idx & 255;    // col in w1 (feature)
    w1t[k * 128 + j] = w1[idx];
}

// ---------------- MLP head: one block (128 threads) per pair ----------------
__global__ __launch_bounds__(128) void mlp_kernel(
    const float* __restrict__ cs, const float* __restrict__ w1t,
    const float* __restrict__ b1, const float* __restrict__ w2,
    const float* __restrict__ b2, float* __restrict__ out)
{
    __shared__ float feat[256];
    __shared__ float part[2];
    const int p = blockIdx.x;
    const int t = threadIdx.x;
    feat[t]       = cs[p * 128 + t];           // user node p
    feat[128 + t] = cs[(B_ + p) * 128 + t];    // item node B+p
    __syncthreads();
    float acc = b1[t];
#pragma unroll 8
    for (int k = 0; k < 256; ++k) acc += feat[k] * w1t[k * 128 + t];
    const float hid = acc > 0.f ? acc : 0.f;
    float v = w2[t] * hid;
#pragma unroll
    for (int off = 32; off > 0; off >>= 1) v += __shfl_down(v, off, 64);
    if ((t & 63) == 0) part[t >> 6] = v;
    __syncthreads();
    if (t == 0) out[p] = part[0] + part[1] + b2[0];
}

extern "C" void kernel_launch(void* const* d_in, const int* in_sizes, int n_in,
                              void* d_out, int out_size, void* d_ws, size_t ws_size,
                              hipStream_t stream) {
    const float* x      = (const float*)d_in[0];
    const int*   src    = (const int*)d_in[1];
    const int*   dst    = (const int*)d_in[2];
    const int*   etype  = (const int*)d_in[3];
    const float* V0     = (const float*)d_in[4];
    const float* comp0  = (const float*)d_in[5];
    const float* loop0  = (const float*)d_in[6];
    const float* bias0  = (const float*)d_in[7];
    const float* Vs     = (const float*)d_in[8];    // [3,2,32,32]
    const float* comps  = (const float*)d_in[9];    // [3,5,2]
    const float* loops  = (const float*)d_in[10];   // [3,32,32]
    const float* biases = (const float*)d_in[11];   // [3,32]
    const float* w1     = (const float*)d_in[12];   // [128,256]
    const float* b1     = (const float*)d_in[13];
    const float* w2     = (const float*)d_in[14];   // [1,128]
    const float* b2     = (const float*)d_in[15];
    float* out = (float*)d_out;

    // Workspace layout (floats)
    float* ws  = (float*)d_ws;
    float* cs  = ws;                       // N*128
    float* xb  = cs + (size_t)N_ * 128;    // N*64
    float* agg = xb + (size_t)N_ * 64;     // N*32
    float* w1t = agg + (size_t)N_ * 32;    // 256*128

    const int nodeBlocks = (N_ + 7) / 8;             // 12500
    const int tanhBlocks = (N_ * 32 + 255) / 256;    // 12500
    const int edgeBlocks = (E_ * 32 + 255) / 256;    // 200000

    transpose_w1_kernel<<<(128 * 256 + 255) / 256, 256, 0, stream>>>(w1, w1t);

    // Layer 0
    node0_kernel<<<nodeBlocks, 256, 0, stream>>>(x, V0, loop0, bias0, xb, agg);
    edge_kernel<<<edgeBlocks, 256, 0, stream>>>(src, dst, etype, comp0, xb, agg);
    tanh_kernel<<<tanhBlocks, 256, 0, stream>>>(agg, cs, 0);

    // Layers 1..3
    for (int i = 1; i < L_; ++i) {
        const float* V     = Vs     + (size_t)(i - 1) * 2048;
        const float* comp  = comps  + (size_t)(i - 1) * 10;
        const float* loopW = loops  + (size_t)(i - 1) * 1024;
        const float* bias  = biases + (size_t)(i - 1) * 32;
        node_kernel<<<nodeBlocks, 256, 0, stream>>>(cs, (i - 1) * 32, V, loopW, bias, xb, agg);
        edge_kernel<<<edgeBlocks, 256, 0, stream>>>(src, dst, etype, comp, xb, agg);
        tanh_kernel<<<tanhBlocks, 256, 0, stream>>>(agg, cs, i * 32);
    }

    // MLP head
    mlp_kernel<<<B_, 128, 0, stream>>>(cs, w1t, b1, w2, b2, out);
}

// Round 2
// 610.574 us; speedup vs baseline: 1.3893x; 1.3893x over previous
//
#include <hip/hip_runtime.h>

// Problem constants (match reference)
constexpr int N_  = 100000;   // nodes
constexpr int E_  = 1600000;  // edges
constexpr int B_  = 2048;     // pairs
constexpr int IN_ = 4;        // input one-hot dim
constexpr int L_  = 4;        // layers

// ======================= CSR build (by dst) =======================
__global__ __launch_bounds__(256) void hist_kernel(
    const int* __restrict__ dst, int* __restrict__ counts)
{
    const int e = blockIdx.x * 256 + threadIdx.x;
    if (e < E_) atomicAdd(&counts[dst[e]], 1);
}

// per-block inclusive scan (256 elems/block) -> tmp, block totals -> blocksum
__global__ __launch_bounds__(256) void scan1_kernel(
    const int* __restrict__ counts, int* __restrict__ tmp,
    int* __restrict__ blocksum, int n)
{
    __shared__ int sh[256];
    const int t = threadIdx.x;
    const int i = blockIdx.x * 256 + t;
    const int v = (i < n) ? counts[i] : 0;
    sh[t] = v; __syncthreads();
#pragma unroll
    for (int off = 1; off < 256; off <<= 1) {
        const int u = (t >= off) ? sh[t - off] : 0;
        __syncthreads();
        sh[t] += u;
        __syncthreads();
    }
    if (i < n) tmp[i] = sh[t];
    if (t == 255) blocksum[blockIdx.x] = sh[255];
}

// single-block exclusive scan of block totals (nb <= 512)
__global__ __launch_bounds__(512) void scan2_kernel(
    const int* __restrict__ blocksum, int* __restrict__ offs, int nb)
{
    __shared__ int sh[512];
    const int t = threadIdx.x;
    const int v = (t < nb) ? blocksum[t] : 0;
    sh[t] = v; __syncthreads();
#pragma unroll
    for (int off = 1; off < 512; off <<= 1) {
        const int u = (t >= off) ? sh[t - off] : 0;
        __syncthreads();
        sh[t] += u;
        __syncthreads();
    }
    if (t < nb) offs[t] = sh[t] - v;   // exclusive
}

// rowptr[i] = exclusive scan; cursor = copy; rowptr[N] = E
__global__ __launch_bounds__(256) void scan3_kernel(
    const int* __restrict__ counts, const int* __restrict__ tmp,
    const int* __restrict__ offs, int* __restrict__ rowptr,
    int* __restrict__ cursor, int n)
{
    const int i = blockIdx.x * 256 + threadIdx.x;
    if (i < n) {
        const int r = tmp[i] - counts[i] + offs[blockIdx.x];
        rowptr[i] = r;
        cursor[i] = r;
    }
    if (i == 0) rowptr[n] = E_;
}

// pack (src | etype<<17) into dst-sorted order
__global__ __launch_bounds__(256) void scatter_kernel(
    const int* __restrict__ src, const int* __restrict__ dst,
    const int* __restrict__ etype, int* __restrict__ cursor,
    int* __restrict__ pack)
{
    const int e = blockIdx.x * 256 + threadIdx.x;
    if (e >= E_) return;
    const int pos = atomicAdd(&cursor[dst[e]], 1);
    pack[pos] = src[e] | (etype[e] << 17);
}

// ======================= Node transforms =======================
// Layer 0 (K = IN = 4): write self-loop+bias into cs slot, xb as [n][h][2]
__global__ __launch_bounds__(256) void node0_kernel(
    const float* __restrict__ x, const float* __restrict__ V0,
    const float* __restrict__ loop0, const float* __restrict__ bias0,
    float* __restrict__ xb, float* __restrict__ cs)
{
    __shared__ float xrow[8][4];
    const int tid  = threadIdx.x;
    const int lane = tid & 31;
    const int nl   = tid >> 5;
    const int node = blockIdx.x * 8 + nl;
    const bool ok  = node < N_;
    if (ok && lane < IN_) xrow[nl][lane] = x[node * IN_ + lane];
    // node-group (32 lanes) is wholly inside one wave: write->read safe
    if (ok) {
        float aL = bias0[lane], a0 = 0.f, a1 = 0.f;
#pragma unroll
        for (int k = 0; k < IN_; ++k) {
            const float hk = xrow[nl][k];
            aL += hk * loop0[k * 32 + lane];
            a0 += hk * V0[k * 32 + lane];           // V0[0,k,:]
            a1 += hk * V0[128 + k * 32 + lane];     // V0[1,k,:]
        }
        cs[node * 128 + lane] = aL;                 // pre-activation self part
        xb[node * 64 + 2 * lane]     = a0;
        xb[node * 64 + 2 * lane + 1] = a1;
    }
}

// Layers 1..3 (K = 32)
__global__ __launch_bounds__(256) void node_kernel(
    const float* __restrict__ csin, int in_off, int out_off,
    const float* __restrict__ V, const float* __restrict__ loopW,
    const float* __restrict__ bias,
    float* __restrict__ xb, float* __restrict__ cs)
{
    __shared__ float hrow[8][32];
    const int tid  = threadIdx.x;
    const int lane = tid & 31;
    const int nl   = tid >> 5;
    const int node = blockIdx.x * 8 + nl;
    const bool ok  = node < N_;
    if (ok) hrow[nl][lane] = csin[node * 128 + in_off + lane];
    if (ok) {
        float aL = bias[lane], a0 = 0.f, a1 = 0.f;
#pragma unroll
        for (int k = 0; k < 32; ++k) {
            const float hk = hrow[nl][k];
            aL += hk * loopW[k * 32 + lane];
            a0 += hk * V[k * 32 + lane];            // V[0,k,:]
            a1 += hk * V[1024 + k * 32 + lane];     // V[1,k,:]
        }
        cs[node * 128 + out_off + lane] = aL;
        xb[node * 64 + 2 * lane]     = a0;
        xb[node * 64 + 2 * lane + 1] = a1;
    }
}

// ======================= Edge gather (no atomics) =======================
// 32 lanes per dst node; lane = h. acc = cs_slot + sum_e c0*xb[s,h,0]+c1*xb[s,h,1]
__global__ __launch_bounds__(256) void gather_kernel(
    const int* __restrict__ rowptr, const int* __restrict__ pack,
    const float* __restrict__ comp, const float* __restrict__ xb,
    float* __restrict__ cs, int out_off)
{
    __shared__ float cmp[16];
    if (threadIdx.x < 10) cmp[threadIdx.x] = comp[threadIdx.x];
    __syncthreads();
    const int tid = blockIdx.x * 256 + threadIdx.x;
    const int n = tid >> 5;
    const int h = tid & 31;
    if (n >= N_) return;
    const int beg = rowptr[n];
    const int end = rowptr[n + 1];
    float acc = cs[n * 128 + out_off + h];
    int e = beg;
    for (; e + 2 <= end; e += 2) {
        const int pk0 = pack[e], pk1 = pack[e + 1];
        const int s0 = pk0 & 0x1FFFF, t0 = pk0 >> 17;
        const int s1 = pk1 & 0x1FFFF, t1 = pk1 >> 17;
        const float2 v0 = *(const float2*)&xb[s0 * 64 + h * 2];
        const float2 v1 = *(const float2*)&xb[s1 * 64 + h * 2];
        acc += cmp[t0 * 2] * v0.x + cmp[t0 * 2 + 1] * v0.y;
        acc += cmp[t1 * 2] * v1.x + cmp[t1 * 2 + 1] * v1.y;
    }
    if (e < end) {
        const int pk = pack[e];
        const int s = pk & 0x1FFFF, t = pk >> 17;
        const float2 v = *(const float2*)&xb[s * 64 + h * 2];
        acc += cmp[t * 2] * v.x + cmp[t * 2 + 1] * v.y;
    }
    cs[n * 128 + out_off + h] = tanhf(acc);
}

// ======================= MLP head =======================
__global__ __launch_bounds__(256) void transpose_w1_kernel(
    const float* __restrict__ w1, float* __restrict__ w1t)
{
    const int idx = blockIdx.x * 256 + threadIdx.x;
    if (idx >= 128 * 256) return;
    const int j = idx >> 8;     // row in w1 (hidden unit)
    const int k = idx & 255;    // col in w1 (feature)
    w1t[k * 128 + j] = w1[idx];
}

__global__ __launch_bounds__(128) void mlp_kernel(
    const float* __restrict__ cs, const float* __restrict__ w1t,
    const float* __restrict__ b1, const float* __restrict__ w2,
    const float* __restrict__ b2, float* __restrict__ out)
{
    __shared__ float feat[256];
    __shared__ float part[2];
    const int p = blockIdx.x;
    const int t = threadIdx.x;
    feat[t]       = cs[p * 128 + t];           // user node p
    feat[128 + t] = cs[(B_ + p) * 128 + t];    // item node B+p
    __syncthreads();
    float acc = b1[t];
#pragma unroll 8
    for (int k = 0; k < 256; ++k) acc += feat[k] * w1t[k * 128 + t];
    const float hid = acc > 0.f ? acc : 0.f;
    float v = w2[t] * hid;
#pragma unroll
    for (int off = 32; off > 0; off >>= 1) v += __shfl_down(v, off, 64);
    if ((t & 63) == 0) part[t >> 6] = v;
    __syncthreads();
    if (t == 0) out[p] = part[0] + part[1] + b2[0];
}

extern "C" void kernel_launch(void* const* d_in, const int* in_sizes, int n_in,
                              void* d_out, int out_size, void* d_ws, size_t ws_size,
                              hipStream_t stream) {
    const float* x      = (const float*)d_in[0];
    const int*   src    = (const int*)d_in[1];
    const int*   dst    = (const int*)d_in[2];
    const int*   etype  = (const int*)d_in[3];
    const float* V0     = (const float*)d_in[4];
    const float* comp0  = (const float*)d_in[5];
    const float* loop0  = (const float*)d_in[6];
    const float* bias0  = (const float*)d_in[7];
    const float* Vs     = (const float*)d_in[8];    // [3,2,32,32]
    const float* comps  = (const float*)d_in[9];    // [3,5,2]
    const float* loops  = (const float*)d_in[10];   // [3,32,32]
    const float* biases = (const float*)d_in[11];   // [3,32]
    const float* w1     = (const float*)d_in[12];   // [128,256]
    const float* b1     = (const float*)d_in[13];
    const float* w2     = (const float*)d_in[14];   // [1,128]
    const float* b2     = (const float*)d_in[15];
    float* out = (float*)d_out;

    // Workspace layout
    float* ws   = (float*)d_ws;
    float* cs   = ws;                        // N*128 floats
    float* xb   = cs + (size_t)N_ * 128;     // N*64 floats, layout [n][h][2]
    float* w1t  = xb + (size_t)N_ * 64;      // 256*128 floats
    int*   pack = (int*)(w1t + 256 * 128);   // E ints
    int*   rowptr = pack + E_;               // N+1 ints
    int*   cursor = rowptr + N_ + 1;         // N ints
    int*   counts = cursor + N_;             // N ints
    int*   tmp    = counts + N_;             // N ints
    int*   blocksum = tmp + N_;              // 512 ints
    int*   offs     = blocksum + 512;        // 512 ints

    const int nodeBlocks = (N_ + 7) / 8;             // 12500
    const int gathBlocks = (N_ * 32 + 255) / 256;    // 12500
    const int edgeBlocks = (E_ + 255) / 256;         // 6250
    const int scanBlocks = (N_ + 255) / 256;         // 391

    // ---- CSR build (by dst) ----
    hipMemsetAsync(counts, 0, (size_t)N_ * sizeof(int), stream);
    hist_kernel<<<edgeBlocks, 256, 0, stream>>>(dst, counts);
    scan1_kernel<<<scanBlocks, 256, 0, stream>>>(counts, tmp, blocksum, N_);
    scan2_kernel<<<1, 512, 0, stream>>>(blocksum, offs, scanBlocks);
    scan3_kernel<<<scanBlocks, 256, 0, stream>>>(counts, tmp, offs, rowptr, cursor, N_);
    scatter_kernel<<<edgeBlocks, 256, 0, stream>>>(src, dst, etype, cursor, pack);

    transpose_w1_kernel<<<(128 * 256 + 255) / 256, 256, 0, stream>>>(w1, w1t);

    // ---- Layer 0 ----
    node0_kernel<<<nodeBlocks, 256, 0, stream>>>(x, V0, loop0, bias0, xb, cs);
    gather_kernel<<<gathBlocks, 256, 0, stream>>>(rowptr, pack, comp0, xb, cs, 0);

    // ---- Layers 1..3 ----
    for (int i = 1; i < L_; ++i) {
        const float* V     = Vs     + (size_t)(i - 1) * 2048;
        const float* comp  = comps  + (size_t)(i - 1) * 10;
        const float* loopW = loops  + (size_t)(i - 1) * 1024;
        const float* bias  = biases + (size_t)(i - 1) * 32;
        node_kernel<<<nodeBlocks, 256, 0, stream>>>(cs, (i - 1) * 32, i * 32, V, loopW, bias, xb, cs);
        gather_kernel<<<gathBlocks, 256, 0, stream>>>(rowptr, pack, comp, xb, cs, i * 32);
    }

    // ---- MLP head ----
    mlp_kernel<<<B_, 128, 0, stream>>>(cs, w1t, b1, w2, b2, out);
}

// Round 3
// 381.558 us; speedup vs baseline: 2.2232x; 1.6002x over previous
//
#include <hip/hip_runtime.h>

// Problem constants (match reference)
constexpr int N_  = 100000;   // nodes
constexpr int E_  = 1600000;  // edges
constexpr int B_  = 2048;     // pairs
constexpr int L_  = 4;        // layers

constexpr int NPB_SHIFT = 9;                    // 512 nodes per bucket
constexpr int NPB = 1 << NPB_SHIFT;
constexpr int KB_ = (N_ + NPB - 1) / NPB;       // 196 buckets
constexpr int PCHUNK = 8192;                    // edges per partition block
constexpr int NPBLK = (E_ + PCHUNK - 1) / PCHUNK; // 196 blocks

// ======================= Stage A: coarse bucket partition =======================
__global__ __launch_bounds__(256) void bhist_kernel(
    const int* __restrict__ dst, int* __restrict__ bhist)
{
    __shared__ int bh[KB_];
    const int t = threadIdx.x;
    for (int i = t; i < KB_; i += 256) bh[i] = 0;
    __syncthreads();
    const int e0 = blockIdx.x * PCHUNK;
    const int e1 = min(e0 + PCHUNK, E_);
    for (int i = e0 + t; i < e1; i += 256) atomicAdd(&bh[dst[i] >> NPB_SHIFT], 1);
    __syncthreads();
    for (int i = t; i < KB_; i += 256) if (bh[i]) atomicAdd(&bhist[i], bh[i]);
}

// single block: exclusive scan of bucket counts -> boffs, bcur
__global__ __launch_bounds__(256) void bscan_kernel(
    const int* __restrict__ bhist, int* __restrict__ boffs, int* __restrict__ bcur)
{
    __shared__ int sh[256];
    const int t = threadIdx.x;
    const int v = (t < KB_) ? bhist[t] : 0;
    sh[t] = v; __syncthreads();
#pragma unroll
    for (int off = 1; off < 256; off <<= 1) {
        const int u = (t >= off) ? sh[t - off] : 0;
        __syncthreads();
        sh[t] += u;
        __syncthreads();
    }
    if (t < KB_) { const int ex = sh[t] - v; boffs[t] = ex; bcur[t] = ex; }
    if (t == 0) boffs[KB_] = E_;
}

// partition edges into bucket-grouped ebuf; pack = src(17) | etype(3)<<17 | dloc(9)<<20
__global__ __launch_bounds__(256) void partition_kernel(
    const int* __restrict__ src, const int* __restrict__ dst,
    const int* __restrict__ etype, int* __restrict__ bcur, int* __restrict__ ebuf)
{
    __shared__ int hist[KB_];
    __shared__ int gbase[KB_];
    __shared__ int lcur[KB_];
    const int t = threadIdx.x;
    for (int i = t; i < KB_; i += 256) { hist[i] = 0; lcur[i] = 0; }
    __syncthreads();
    const int e0 = blockIdx.x * PCHUNK;
    const int e1 = min(e0 + PCHUNK, E_);
    for (int i = e0 + t; i < e1; i += 256) atomicAdd(&hist[dst[i] >> NPB_SHIFT], 1);
    __syncthreads();
    for (int i = t; i < KB_; i += 256) if (hist[i]) gbase[i] = atomicAdd(&bcur[i], hist[i]);
    __syncthreads();
    for (int i = e0 + t; i < e1; i += 256) {
        const int d = dst[i];
        const int b = d >> NPB_SHIFT;
        const int lp = atomicAdd(&lcur[b], 1);
        ebuf[gbase[b] + lp] = src[i] | (etype[i] << 17) | ((d & (NPB - 1)) << 20);
    }
}

// per-bucket node histogram via LDS atomics -> counts[N]
__global__ __launch_bounds__(256) void bnodehist_kernel(
    const int* __restrict__ boffs, const int* __restrict__ ebuf,
    int* __restrict__ counts)
{
    __shared__ int cnt[NPB];
    const int b = blockIdx.x, t = threadIdx.x;
    cnt[t] = 0; cnt[t + 256] = 0;
    __syncthreads();
    const int s0 = boffs[b], s1 = boffs[b + 1];
    for (int i = s0 + t; i < s1; i += 256) atomicAdd(&cnt[ebuf[i] >> 20], 1);
    __syncthreads();
    const int base = b << NPB_SHIFT;
    if (base + t < N_)       counts[base + t]       = cnt[t];
    if (base + t + 256 < N_) counts[base + t + 256] = cnt[t + 256];
}

// ======================= N-element scan for rowptr =======================
__global__ __launch_bounds__(256) void scan1_kernel(
    const int* __restrict__ counts, int* __restrict__ tmp,
    int* __restrict__ blocksum, int n)
{
    __shared__ int sh[256];
    const int t = threadIdx.x;
    const int i = blockIdx.x * 256 + t;
    const int v = (i < n) ? counts[i] : 0;
    sh[t] = v; __syncthreads();
#pragma unroll
    for (int off = 1; off < 256; off <<= 1) {
        const int u = (t >= off) ? sh[t - off] : 0;
        __syncthreads();
        sh[t] += u;
        __syncthreads();
    }
    if (i < n) tmp[i] = sh[t];
    if (t == 255) blocksum[blockIdx.x] = sh[255];
}

__global__ __launch_bounds__(512) void scan2_kernel(
    const int* __restrict__ blocksum, int* __restrict__ offs, int nb)
{
    __shared__ int sh[512];
    const int t = threadIdx.x;
    const int v = (t < nb) ? blocksum[t] : 0;
    sh[t] = v; __syncthreads();
#pragma unroll
    for (int off = 1; off < 512; off <<= 1) {
        const int u = (t >= off) ? sh[t - off] : 0;
        __syncthreads();
        sh[t] += u;
        __syncthreads();
    }
    if (t < nb) offs[t] = sh[t] - v;   // exclusive
}

__global__ __launch_bounds__(256) void scan3_kernel(
    const int* __restrict__ counts, const int* __restrict__ tmp,
    const int* __restrict__ offs, int* __restrict__ rowptr, int n)
{
    const int i = blockIdx.x * 256 + threadIdx.x;
    if (i < n) rowptr[i] = tmp[i] - counts[i] + offs[blockIdx.x];
    if (i == 0) rowptr[n] = E_;
}

// ======================= Stage B: fine scatter (L2-local) =======================
__global__ __launch_bounds__(256) void bscatter_kernel(
    const int* __restrict__ boffs, const int* __restrict__ rowptr,
    const int* __restrict__ ebuf, int* __restrict__ pack)
{
    __shared__ int cur[NPB];
    const int b = blockIdx.x, t = threadIdx.x;
    const int base = b << NPB_SHIFT;
    cur[t]       = (base + t       < N_) ? rowptr[base + t]       : 0;
    cur[t + 256] = (base + t + 256 < N_) ? rowptr[base + t + 256] : 0;
    __syncthreads();
    const int s0 = boffs[b], s1 = boffs[b + 1];
    for (int i = s0 + t; i < s1; i += 256) {
        const int p = ebuf[i];
        const int pos = atomicAdd(&cur[p >> 20], 1);
        pack[pos] = p & 0xFFFFF;   // src | etype<<17
    }
}

// ======================= Layer 0 fused gather (K = 4) =======================
// 32 lanes per dst node; 8 edge slots x 4 input dims.
__global__ __launch_bounds__(256) void gather0_kernel(
    const float* __restrict__ x, const int* __restrict__ rowptr,
    const int* __restrict__ pack, const float* __restrict__ comp,
    const float* __restrict__ V0, const float* __restrict__ loop0,
    const float* __restrict__ bias0,
    float* __restrict__ cs, float* __restrict__ hout)
{
    __shared__ float hs[8][12];   // [g][0..3]=x_own [4..7]=a0 [8..11]=a1
    __shared__ float cmp[10];
    const int t = threadIdx.x, lane = t & 31, g = t >> 5;
    if (t < 10) cmp[t] = comp[t];
    const int n = blockIdx.x * 8 + g;      // grid exact: N_/8 blocks
    const int k4 = lane & 3, slot = lane >> 2;
    if (lane < 4) hs[g][lane] = x[n * 4 + lane];
    __syncthreads();
    const int beg = rowptr[n], end = rowptr[n + 1];
    float a0 = 0.f, a1 = 0.f;
    for (int e = beg + slot; e < end; e += 8) {
        const int p = pack[e];
        const int s = p & 0x1FFFF, tt = (p >> 17) & 7;
        const float v = x[s * 4 + k4];
        a0 += cmp[tt * 2] * v;
        a1 += cmp[tt * 2 + 1] * v;
    }
    a0 += __shfl_xor(a0, 4);  a1 += __shfl_xor(a1, 4);
    a0 += __shfl_xor(a0, 8);  a1 += __shfl_xor(a1, 8);
    a0 += __shfl_xor(a0, 16); a1 += __shfl_xor(a1, 16);
    if (lane < 4) { hs[g][4 + lane] = a0; hs[g][8 + lane] = a1; }
    __syncthreads();
    float o = bias0[lane];
#pragma unroll
    for (int k = 0; k < 4; ++k) {
        o += hs[g][k] * loop0[k * 32 + lane]
           + hs[g][4 + k] * V0[k * 32 + lane]
           + hs[g][8 + k] * V0[128 + k * 32 + lane];
    }
    const float r = tanhf(o);
    cs[n * 128 + lane] = r;
    hout[n * 32 + lane] = r;
}

// ======================= Layers 1..3 fused gather (K = 32) =======================
// aggregate raw h[src] per basis coeff, then per-node matvecs + self-loop + tanh.
__global__ __launch_bounds__(256) void gather_kernel(
    const float* __restrict__ hin, const int* __restrict__ rowptr,
    const int* __restrict__ pack, const float* __restrict__ comp,
    const float* __restrict__ V, const float* __restrict__ loopW,
    const float* __restrict__ bias,
    float* __restrict__ cs, float* __restrict__ hout,
    int out_off, int writeH)
{
    __shared__ float hs[8][96];   // [g][0..31]=h_own [32..63]=a0 [64..95]=a1
    __shared__ float cmp[10];
    const int t = threadIdx.x, lane = t & 31, g = t >> 5;
    if (t < 10) cmp[t] = comp[t];
    const int n = blockIdx.x * 8 + g;      // grid exact
    hs[g][lane] = hin[n * 32 + lane];
    __syncthreads();
    const int beg = rowptr[n], end = rowptr[n + 1];
    float a0 = 0.f, a1 = 0.f;
    int e = beg;
    for (; e + 2 <= end; e += 2) {
        const int p0 = pack[e], p1 = pack[e + 1];
        const float v0 = hin[(p0 & 0x1FFFF) * 32 + lane];
        const float v1 = hin[(p1 & 0x1FFFF) * 32 + lane];
        const int t0 = (p0 >> 17) & 7, t1 = (p1 >> 17) & 7;
        a0 += cmp[t0 * 2] * v0 + cmp[t1 * 2] * v1;
        a1 += cmp[t0 * 2 + 1] * v0 + cmp[t1 * 2 + 1] * v1;
    }
    if (e < end) {
        const int p = pack[e];
        const float v = hin[(p & 0x1FFFF) * 32 + lane];
        const int tt = (p >> 17) & 7;
        a0 += cmp[tt * 2] * v;
        a1 += cmp[tt * 2 + 1] * v;
    }
    hs[g][32 + lane] = a0;
    hs[g][64 + lane] = a1;
    __syncthreads();
    float o = bias[lane];
#pragma unroll 8
    for (int k = 0; k < 32; ++k) {
        o += hs[g][k] * loopW[k * 32 + lane]
           + hs[g][32 + k] * V[k * 32 + lane]
           + hs[g][64 + k] * V[1024 + k * 32 + lane];
    }
    const float r = tanhf(o);
    cs[n * 128 + out_off + lane] = r;
    if (writeH) hout[n * 32 + lane] = r;
}

// ======================= MLP head =======================
__global__ __launch_bounds__(256) void transpose_w1_kernel(
    const float* __restrict__ w1, float* __restrict__ w1t)
{
    const int idx = blockIdx.x * 256 + threadIdx.x;
    if (idx >= 128 * 256) return;
    const int j = idx >> 8;
    const int k = idx & 255;
    w1t[k * 128 + j] = w1[idx];
}

__global__ __launch_bounds__(128) void mlp_kernel(
    const float* __restrict__ cs, const float* __restrict__ w1t,
    const float* __restrict__ b1, const float* __restrict__ w2,
    const float* __restrict__ b2, float* __restrict__ out)
{
    __shared__ float feat[256];
    __shared__ float part[2];
    const int p = blockIdx.x;
    const int t = threadIdx.x;
    feat[t]       = cs[p * 128 + t];
    feat[128 + t] = cs[(B_ + p) * 128 + t];
    __syncthreads();
    float acc = b1[t];
#pragma unroll 8
    for (int k = 0; k < 256; ++k) acc += feat[k] * w1t[k * 128 + t];
    const float hid = acc > 0.f ? acc : 0.f;
    float v = w2[t] * hid;
#pragma unroll
    for (int off = 32; off > 0; off >>= 1) v += __shfl_down(v, off, 64);
    if ((t & 63) == 0) part[t >> 6] = v;
    __syncthreads();
    if (t == 0) out[p] = part[0] + part[1] + b2[0];
}

extern "C" void kernel_launch(void* const* d_in, const int* in_sizes, int n_in,
                              void* d_out, int out_size, void* d_ws, size_t ws_size,
                              hipStream_t stream) {
    const float* x      = (const float*)d_in[0];
    const int*   src    = (const int*)d_in[1];
    const int*   dst    = (const int*)d_in[2];
    const int*   etype  = (const int*)d_in[3];
    const float* V0     = (const float*)d_in[4];
    const float* comp0  = (const float*)d_in[5];
    const float* loop0  = (const float*)d_in[6];
    const float* bias0  = (const float*)d_in[7];
    const float* Vs     = (const float*)d_in[8];    // [3,2,32,32]
    const float* comps  = (const float*)d_in[9];    // [3,5,2]
    const float* loops  = (const float*)d_in[10];   // [3,32,32]
    const float* biases = (const float*)d_in[11];   // [3,32]
    const float* w1     = (const float*)d_in[12];   // [128,256]
    const float* b1     = (const float*)d_in[13];
    const float* w2     = (const float*)d_in[14];   // [1,128]
    const float* b2     = (const float*)d_in[15];
    float* out = (float*)d_out;

    // Workspace layout (floats / ints)
    float* ws   = (float*)d_ws;
    float* cs   = ws;                         // N*128
    float* hA   = cs + (size_t)N_ * 128;      // N*32
    float* hB   = hA + (size_t)N_ * 32;       // N*32
    float* w1t  = hB + (size_t)N_ * 32;       // 256*128
    int* ebuf     = (int*)(w1t + 256 * 128);  // E
    int* pack     = ebuf + E_;                // E
    int* rowptr   = pack + E_;                // N+1
    int* counts   = rowptr + N_ + 1;          // N
    int* tmp      = counts + N_;              // N
    int* blocksum = tmp + N_;                 // 512
    int* offs     = blocksum + 512;           // 512
    int* bhist    = offs + 512;               // KB_
    int* boffs    = bhist + KB_;              // KB_+1
    int* bcur     = boffs + KB_ + 1;          // KB_

    const int gathBlocks = N_ / 8;            // 12500 (exact)
    const int scanBlocks = (N_ + 255) / 256;  // 391

    // ---- CSR build (bucketed counting sort by dst) ----
    hipMemsetAsync(bhist, 0, KB_ * sizeof(int), stream);
    bhist_kernel<<<NPBLK, 256, 0, stream>>>(dst, bhist);
    bscan_kernel<<<1, 256, 0, stream>>>(bhist, boffs, bcur);
    partition_kernel<<<NPBLK, 256, 0, stream>>>(src, dst, etype, bcur, ebuf);
    bnodehist_kernel<<<KB_, 256, 0, stream>>>(boffs, ebuf, counts);
    scan1_kernel<<<scanBlocks, 256, 0, stream>>>(counts, tmp, blocksum, N_);
    scan2_kernel<<<1, 512, 0, stream>>>(blocksum, offs, scanBlocks);
    scan3_kernel<<<scanBlocks, 256, 0, stream>>>(counts, tmp, offs, rowptr, N_);
    bscatter_kernel<<<KB_, 256, 0, stream>>>(boffs, rowptr, ebuf, pack);

    transpose_w1_kernel<<<(128 * 256 + 255) / 256, 256, 0, stream>>>(w1, w1t);

    // ---- Layer 0 ----
    gather0_kernel<<<gathBlocks, 256, 0, stream>>>(x, rowptr, pack, comp0, V0, loop0, bias0, cs, hA);

    // ---- Layers 1..3 ----
    const float* hbufs[2] = { hA, hB };
    for (int i = 1; i < L_; ++i) {
        const float* V     = Vs     + (size_t)(i - 1) * 2048;
        const float* comp  = comps  + (size_t)(i - 1) * 10;
        const float* loopW = loops  + (size_t)(i - 1) * 1024;
        const float* bias  = biases + (size_t)(i - 1) * 32;
        const float* hin = hbufs[(i - 1) & 1];
        float* hout      = (float*)hbufs[i & 1];
        gather_kernel<<<gathBlocks, 256, 0, stream>>>(
            hin, rowptr, pack, comp, V, loopW, bias, cs, hout, i * 32, (i < L_ - 1) ? 1 : 0);
    }

    // ---- MLP head ----
    mlp_kernel<<<B_, 128, 0, stream>>>(cs, w1t, b1, w2, b2, out);
}

// Round 4
// 298.183 us; speedup vs baseline: 2.8449x; 1.2796x over previous
//
#include <hip/hip_runtime.h>
#include <hip/hip_fp16.h>

// Problem constants (match reference)
constexpr int N_  = 100000;   // nodes
constexpr int E_  = 1600000;  // edges
constexpr int B_  = 2048;     // pairs
constexpr int L_  = 4;        // layers

constexpr int NPB_SHIFT = 9;                    // 512 nodes per bucket
constexpr int NPB = 1 << NPB_SHIFT;
constexpr int KB_ = (N_ + NPB - 1) / NPB;       // 196 buckets
constexpr int PCHUNK = 8192;                    // edges per partition block
constexpr int NPBLK = (E_ + PCHUNK - 1) / PCHUNK; // 196 blocks

// ======================= Stage A: coarse bucket partition =======================
__global__ __launch_bounds__(256) void bhist_kernel(
    const int* __restrict__ dst, int* __restrict__ bhist)
{
    __shared__ int bh[KB_];
    const int t = threadIdx.x;
    for (int i = t; i < KB_; i += 256) bh[i] = 0;
    __syncthreads();
    const int e0 = blockIdx.x * PCHUNK;
    const int e1 = min(e0 + PCHUNK, E_);
    for (int i = e0 + t; i < e1; i += 256) atomicAdd(&bh[dst[i] >> NPB_SHIFT], 1);
    __syncthreads();
    for (int i = t; i < KB_; i += 256) if (bh[i]) atomicAdd(&bhist[i], bh[i]);
}

// single block: exclusive scan of bucket counts -> boffs, bcur
__global__ __launch_bounds__(256) void bscan_kernel(
    const int* __restrict__ bhist, int* __restrict__ boffs, int* __restrict__ bcur)
{
    __shared__ int sh[256];
    const int t = threadIdx.x;
    const int v = (t < KB_) ? bhist[t] : 0;
    sh[t] = v; __syncthreads();
#pragma unroll
    for (int off = 1; off < 256; off <<= 1) {
        const int u = (t >= off) ? sh[t - off] : 0;
        __syncthreads();
        sh[t] += u;
        __syncthreads();
    }
    if (t < KB_) { const int ex = sh[t] - v; boffs[t] = ex; bcur[t] = ex; }
    if (t == 0) boffs[KB_] = E_;
}

// partition edges into bucket-grouped ebuf; pack = src(17) | etype(3)<<17 | dloc(9)<<20
__global__ __launch_bounds__(256) void partition_kernel(
    const int* __restrict__ src, const int* __restrict__ dst,
    const int* __restrict__ etype, int* __restrict__ bcur, int* __restrict__ ebuf)
{
    __shared__ int hist[KB_];
    __shared__ int gbase[KB_];
    __shared__ int lcur[KB_];
    const int t = threadIdx.x;
    for (int i = t; i < KB_; i += 256) { hist[i] = 0; lcur[i] = 0; }
    __syncthreads();
    const int e0 = blockIdx.x * PCHUNK;
    const int e1 = min(e0 + PCHUNK, E_);
    for (int i = e0 + t; i < e1; i += 256) atomicAdd(&hist[dst[i] >> NPB_SHIFT], 1);
    __syncthreads();
    for (int i = t; i < KB_; i += 256) if (hist[i]) gbase[i] = atomicAdd(&bcur[i], hist[i]);
    __syncthreads();
    for (int i = e0 + t; i < e1; i += 256) {
        const int d = dst[i];
        const int b = d >> NPB_SHIFT;
        const int lp = atomicAdd(&lcur[b], 1);
        ebuf[gbase[b] + lp] = src[i] | (etype[i] << 17) | ((d & (NPB - 1)) << 20);
    }
}

// per-bucket node histogram via LDS atomics -> counts[N]
__global__ __launch_bounds__(256) void bnodehist_kernel(
    const int* __restrict__ boffs, const int* __restrict__ ebuf,
    int* __restrict__ counts)
{
    __shared__ int cnt[NPB];
    const int b = blockIdx.x, t = threadIdx.x;
    cnt[t] = 0; cnt[t + 256] = 0;
    __syncthreads();
    const int s0 = boffs[b], s1 = boffs[b + 1];
    for (int i = s0 + t; i < s1; i += 256) atomicAdd(&cnt[ebuf[i] >> 20], 1);
    __syncthreads();
    const int base = b << NPB_SHIFT;
    if (base + t < N_)       counts[base + t]       = cnt[t];
    if (base + t + 256 < N_) counts[base + t + 256] = cnt[t + 256];
}

// ======================= N-element scan for rowptr =======================
__global__ __launch_bounds__(256) void scan1_kernel(
    const int* __restrict__ counts, int* __restrict__ tmp,
    int* __restrict__ blocksum, int n)
{
    __shared__ int sh[256];
    const int t = threadIdx.x;
    const int i = blockIdx.x * 256 + t;
    const int v = (i < n) ? counts[i] : 0;
    sh[t] = v; __syncthreads();
#pragma unroll
    for (int off = 1; off < 256; off <<= 1) {
        const int u = (t >= off) ? sh[t - off] : 0;
        __syncthreads();
        sh[t] += u;
        __syncthreads();
    }
    if (i < n) tmp[i] = sh[t];
    if (t == 255) blocksum[blockIdx.x] = sh[255];
}

__global__ __launch_bounds__(512) void scan2_kernel(
    const int* __restrict__ blocksum, int* __restrict__ offs, int nb)
{
    __shared__ int sh[512];
    const int t = threadIdx.x;
    const int v = (t < nb) ? blocksum[t] : 0;
    sh[t] = v; __syncthreads();
#pragma unroll
    for (int off = 1; off < 512; off <<= 1) {
        const int u = (t >= off) ? sh[t - off] : 0;
        __syncthreads();
        sh[t] += u;
        __syncthreads();
    }
    if (t < nb) offs[t] = sh[t] - v;   // exclusive
}

__global__ __launch_bounds__(256) void scan3_kernel(
    const int* __restrict__ counts, const int* __restrict__ tmp,
    const int* __restrict__ offs, int* __restrict__ rowptr, int n)
{
    const int i = blockIdx.x * 256 + threadIdx.x;
    if (i < n) rowptr[i] = tmp[i] - counts[i] + offs[blockIdx.x];
    if (i == 0) rowptr[n] = E_;
}

// ======================= Stage B: fine scatter (L2-local) =======================
__global__ __launch_bounds__(256) void bscatter_kernel(
    const int* __restrict__ boffs, const int* __restrict__ rowptr,
    const int* __restrict__ ebuf, int* __restrict__ pack)
{
    __shared__ int cur[NPB];
    const int b = blockIdx.x, t = threadIdx.x;
    const int base = b << NPB_SHIFT;
    cur[t]       = (base + t       < N_) ? rowptr[base + t]       : 0;
    cur[t + 256] = (base + t + 256 < N_) ? rowptr[base + t + 256] : 0;
    __syncthreads();
    const int s0 = boffs[b], s1 = boffs[b + 1];
    for (int i = s0 + t; i < s1; i += 256) {
        const int p = ebuf[i];
        const int pos = atomicAdd(&cur[p >> 20], 1);
        pack[pos] = p & 0xFFFFF;   // src | etype<<17
    }
}

// ======================= Layer 0 fused gather (K = 4) =======================
// 32 lanes per dst node; 8 edge slots x 4 input dims.
__global__ __launch_bounds__(256) void gather0_kernel(
    const float* __restrict__ x, const int* __restrict__ rowptr,
    const int* __restrict__ pack, const float* __restrict__ comp,
    const float* __restrict__ V0, const float* __restrict__ loop0,
    const float* __restrict__ bias0,
    float* __restrict__ cs, __half* __restrict__ hout)
{
    __shared__ float hs[8][12];   // [g][0..3]=x_own [4..7]=a0 [8..11]=a1
    __shared__ float cmp[10];
    const int t = threadIdx.x, lane = t & 31, g = t >> 5;
    if (t < 10) cmp[t] = comp[t];
    const int n = blockIdx.x * 8 + g;      // grid exact: N_/8 blocks
    const int k4 = lane & 3, slot = lane >> 2;
    if (lane < 4) hs[g][lane] = x[n * 4 + lane];
    __syncthreads();
    const int beg = rowptr[n], end = rowptr[n + 1];
    float a0 = 0.f, a1 = 0.f;
    for (int e = beg + slot; e < end; e += 8) {
        const int p = pack[e];
        const int s = p & 0x1FFFF, tt = (p >> 17) & 7;
        const float v = x[s * 4 + k4];
        a0 += cmp[tt * 2] * v;
        a1 += cmp[tt * 2 + 1] * v;
    }
    a0 += __shfl_xor(a0, 4);  a1 += __shfl_xor(a1, 4);
    a0 += __shfl_xor(a0, 8);  a1 += __shfl_xor(a1, 8);
    a0 += __shfl_xor(a0, 16); a1 += __shfl_xor(a1, 16);
    if (lane < 4) { hs[g][4 + lane] = a0; hs[g][8 + lane] = a1; }
    __syncthreads();
    float o = bias0[lane];
#pragma unroll
    for (int k = 0; k < 4; ++k) {
        o += hs[g][k] * loop0[k * 32 + lane]
           + hs[g][4 + k] * V0[k * 32 + lane]
           + hs[g][8 + k] * V0[128 + k * 32 + lane];
    }
    const float r = tanhf(o);
    cs[n * 128 + lane] = r;
    hout[n * 32 + lane] = __float2half(r);
}

// ======================= Layers 1..3 fused gather (K = 32) =======================
// 4 lanes per edge (8 edges in flight per 32-lane group); fp16 neighbor h.
// Self-loop h read exactly (fp32) from cs.
__global__ __launch_bounds__(256) void gather_kernel(
    const float* __restrict__ csin, int in_off,
    const __half* __restrict__ hin, const int* __restrict__ rowptr,
    const int* __restrict__ pack, const float* __restrict__ comp,
    const float* __restrict__ V, const float* __restrict__ loopW,
    const float* __restrict__ bias,
    float* __restrict__ cs, __half* __restrict__ hout,
    int out_off, int writeH)
{
    __shared__ float hs[8][96];   // [g][0..31]=h_own [32..63]=a0 [64..95]=a1
    __shared__ float cmp[10];
    const int t = threadIdx.x, lane = t & 31, g = t >> 5;
    if (t < 10) cmp[t] = comp[t];
    const int n = blockIdx.x * 8 + g;      // grid exact
    hs[g][lane] = csin[n * 128 + in_off + lane];
    __syncthreads();
    const int beg = rowptr[n], end = rowptr[n + 1];
    const int sg = lane >> 2;   // edge slot 0..7
    const int c  = lane & 3;    // half-chunk: dims 8c..8c+7
    float a0[8] = {0.f,0.f,0.f,0.f,0.f,0.f,0.f,0.f};
    float a1[8] = {0.f,0.f,0.f,0.f,0.f,0.f,0.f,0.f};
#pragma unroll 2
    for (int e0 = beg; e0 < end; e0 += 8) {
        const int e = e0 + sg;
        const bool ok = e < end;
        const int p = pack[ok ? e : beg];
        const int s = p & 0x1FFFF;
        const int tt = (p >> 17) & 7;
        const float c0 = ok ? cmp[tt * 2]     : 0.f;
        const float c1 = ok ? cmp[tt * 2 + 1] : 0.f;
        const uint4 u = *(const uint4*)(hin + (size_t)s * 32 + c * 8);  // 8 halves
        const __half2* hp = (const __half2*)&u;
#pragma unroll
        for (int k = 0; k < 4; ++k) {
            const float2 f = __half22float2(hp[k]);
            a0[2 * k]     += c0 * f.x;
            a0[2 * k + 1] += c0 * f.y;
            a1[2 * k]     += c1 * f.x;
            a1[2 * k + 1] += c1 * f.y;
        }
    }
    // reduce across the 8 edge slots (stay within the 32-lane group)
#pragma unroll
    for (int k = 0; k < 8; ++k) {
        a0[k] += __shfl_xor(a0[k], 4);
        a0[k] += __shfl_xor(a0[k], 8);
        a0[k] += __shfl_xor(a0[k], 16);
        a1[k] += __shfl_xor(a1[k], 4);
        a1[k] += __shfl_xor(a1[k], 8);
        a1[k] += __shfl_xor(a1[k], 16);
    }
    if (lane < 4) {
#pragma unroll
        for (int k = 0; k < 8; ++k) {
            hs[g][32 + c * 8 + k] = a0[k];
            hs[g][64 + c * 8 + k] = a1[k];
        }
    }
    __syncthreads();
    float o = bias[lane];
#pragma unroll 8
    for (int k = 0; k < 32; ++k) {
        o += hs[g][k] * loopW[k * 32 + lane]
           + hs[g][32 + k] * V[k * 32 + lane]
           + hs[g][64 + k] * V[1024 + k * 32 + lane];
    }
    const float r = tanhf(o);
    cs[n * 128 + out_off + lane] = r;
    if (writeH) hout[n * 32 + lane] = __float2half(r);
}

// ======================= MLP head =======================
__global__ __launch_bounds__(256) void transpose_w1_kernel(
    const float* __restrict__ w1, float* __restrict__ w1t)
{
    const int idx = blockIdx.x * 256 + threadIdx.x;
    if (idx >= 128 * 256) return;
    const int j = idx >> 8;
    const int k = idx & 255;
    w1t[k * 128 + j] = w1[idx];
}

__global__ __launch_bounds__(128) void mlp_kernel(
    const float* __restrict__ cs, const float* __restrict__ w1t,
    const float* __restrict__ b1, const float* __restrict__ w2,
    const float* __restrict__ b2, float* __restrict__ out)
{
    __shared__ float feat[256];
    __shared__ float part[2];
    const int p = blockIdx.x;
    const int t = threadIdx.x;
    feat[t]       = cs[p * 128 + t];
    feat[128 + t] = cs[(B_ + p) * 128 + t];
    __syncthreads();
    float acc = b1[t];
#pragma unroll 8
    for (int k = 0; k < 256; ++k) acc += feat[k] * w1t[k * 128 + t];
    const float hid = acc > 0.f ? acc : 0.f;
    float v = w2[t] * hid;
#pragma unroll
    for (int off = 32; off > 0; off >>= 1) v += __shfl_down(v, off, 64);
    if ((t & 63) == 0) part[t >> 6] = v;
    __syncthreads();
    if (t == 0) out[p] = part[0] + part[1] + b2[0];
}

extern "C" void kernel_launch(void* const* d_in, const int* in_sizes, int n_in,
                              void* d_out, int out_size, void* d_ws, size_t ws_size,
                              hipStream_t stream) {
    const float* x      = (const float*)d_in[0];
    const int*   src    = (const int*)d_in[1];
    const int*   dst    = (const int*)d_in[2];
    const int*   etype  = (const int*)d_in[3];
    const float* V0     = (const float*)d_in[4];
    const float* comp0  = (const float*)d_in[5];
    const float* loop0  = (const float*)d_in[6];
    const float* bias0  = (const float*)d_in[7];
    const float* Vs     = (const float*)d_in[8];    // [3,2,32,32]
    const float* comps  = (const float*)d_in[9];    // [3,5,2]
    const float* loops  = (const float*)d_in[10];   // [3,32,32]
    const float* biases = (const float*)d_in[11];   // [3,32]
    const float* w1     = (const float*)d_in[12];   // [128,256]
    const float* b1     = (const float*)d_in[13];
    const float* w2     = (const float*)d_in[14];   // [1,128]
    const float* b2     = (const float*)d_in[15];
    float* out = (float*)d_out;

    // Workspace layout
    float* ws   = (float*)d_ws;
    float* cs   = ws;                          // N*128 floats
    float* w1t  = cs + (size_t)N_ * 128;       // 256*128 floats
    __half* hA  = (__half*)(w1t + 256 * 128);  // N*32 halves
    __half* hB  = hA + (size_t)N_ * 32;        // N*32 halves
    int* ebuf     = (int*)(hB + (size_t)N_ * 32); // E
    int* pack     = ebuf + E_;                 // E
    int* rowptr   = pack + E_;                 // N+1
    int* counts   = rowptr + N_ + 1;           // N
    int* tmp      = counts + N_;               // N
    int* blocksum = tmp + N_;                  // 512
    int* offs     = blocksum + 512;            // 512
    int* bhist    = offs + 512;                // KB_
    int* boffs    = bhist + KB_;               // KB_+1
    int* bcur     = boffs + KB_ + 1;           // KB_

    const int gathBlocks = N_ / 8;             // 12500 (exact)
    const int scanBlocks = (N_ + 255) / 256;   // 391

    // ---- CSR build (bucketed counting sort by dst) ----
    hipMemsetAsync(bhist, 0, KB_ * sizeof(int), stream);
    bhist_kernel<<<NPBLK, 256, 0, stream>>>(dst, bhist);
    bscan_kernel<<<1, 256, 0, stream>>>(bhist, boffs, bcur);
    partition_kernel<<<NPBLK, 256, 0, stream>>>(src, dst, etype, bcur, ebuf);
    bnodehist_kernel<<<KB_, 256, 0, stream>>>(boffs, ebuf, counts);
    scan1_kernel<<<scanBlocks, 256, 0, stream>>>(counts, tmp, blocksum, N_);
    scan2_kernel<<<1, 512, 0, stream>>>(blocksum, offs, scanBlocks);
    scan3_kernel<<<scanBlocks, 256, 0, stream>>>(counts, tmp, offs, rowptr, N_);
    bscatter_kernel<<<KB_, 256, 0, stream>>>(boffs, rowptr, ebuf, pack);

    transpose_w1_kernel<<<(128 * 256 + 255) / 256, 256, 0, stream>>>(w1, w1t);

    // ---- Layer 0 ----
    gather0_kernel<<<gathBlocks, 256, 0, stream>>>(x, rowptr, pack, comp0, V0, loop0, bias0, cs, hA);

    // ---- Layers 1..3 ----
    __half* hbufs[2] = { hA, hB };
    for (int i = 1; i < L_; ++i) {
        const float* V     = Vs     + (size_t)(i - 1) * 2048;
        const float* comp  = comps  + (size_t)(i - 1) * 10;
        const float* loopW = loops  + (size_t)(i - 1) * 1024;
        const float* bias  = biases + (size_t)(i - 1) * 32;
        const __half* hin = hbufs[(i - 1) & 1];
        __half* hout      = hbufs[i & 1];
        gather_kernel<<<gathBlocks, 256, 0, stream>>>(
            cs, (i - 1) * 32, hin, rowptr, pack, comp, V, loopW, bias,
            cs, hout, i * 32, (i < L_ - 1) ? 1 : 0);
    }

    // ---- MLP head ----
    mlp_kernel<<<B_, 128, 0, stream>>>(cs, w1t, b1, w2, b2, out);
}

// Round 5
// 244.024 us; speedup vs baseline: 3.4763x; 1.2219x over previous
//
#include <hip/hip_runtime.h>
#include <hip/hip_fp16.h>

// Problem constants (match reference)
constexpr int N_  = 100000;   // nodes
constexpr int E_  = 1600000;  // edges
constexpr int B_  = 2048;     // pairs
constexpr int L_  = 4;        // layers
constexpr int NT_ = 2 * B_;   // 4096 target nodes (users+items) read by MLP

constexpr int NPB_SHIFT = 9;                    // 512 nodes per bucket
constexpr int NPB = 1 << NPB_SHIFT;
constexpr int KB_ = (N_ + NPB - 1) / NPB;       // 196 buckets
constexpr int PCHUNK = 8192;                    // edges per partition block
constexpr int NPBLK = (E_ + PCHUNK - 1) / PCHUNK; // 196 blocks

// ======================= Stage A: coarse bucket partition =======================
__global__ __launch_bounds__(256) void bhist_kernel(
    const int* __restrict__ dst, int* __restrict__ bhist)
{
    __shared__ int bh[KB_];
    const int t = threadIdx.x;
    for (int i = t; i < KB_; i += 256) bh[i] = 0;
    __syncthreads();
    const int e0 = blockIdx.x * PCHUNK;
    const int e1 = min(e0 + PCHUNK, E_);
    for (int i = e0 + t; i < e1; i += 256) atomicAdd(&bh[dst[i] >> NPB_SHIFT], 1);
    __syncthreads();
    for (int i = t; i < KB_; i += 256) if (bh[i]) atomicAdd(&bhist[i], bh[i]);
}

// single block: exclusive scan of bucket counts -> boffs, bcur
__global__ __launch_bounds__(256) void bscan_kernel(
    const int* __restrict__ bhist, int* __restrict__ boffs, int* __restrict__ bcur)
{
    __shared__ int sh[256];
    const int t = threadIdx.x;
    const int v = (t < KB_) ? bhist[t] : 0;
    sh[t] = v; __syncthreads();
#pragma unroll
    for (int off = 1; off < 256; off <<= 1) {
        const int u = (t >= off) ? sh[t - off] : 0;
        __syncthreads();
        sh[t] += u;
        __syncthreads();
    }
    if (t < KB_) { const int ex = sh[t] - v; boffs[t] = ex; bcur[t] = ex; }
    if (t == 0) boffs[KB_] = E_;
}

// partition edges into bucket-grouped ebuf; pack = src(17) | etype(3)<<17 | dloc(9)<<20
__global__ __launch_bounds__(256) void partition_kernel(
    const int* __restrict__ src, const int* __restrict__ dst,
    const int* __restrict__ etype, int* __restrict__ bcur, int* __restrict__ ebuf)
{
    __shared__ int hist[KB_];
    __shared__ int gbase[KB_];
    __shared__ int lcur[KB_];
    const int t = threadIdx.x;
    for (int i = t; i < KB_; i += 256) { hist[i] = 0; lcur[i] = 0; }
    __syncthreads();
    const int e0 = blockIdx.x * PCHUNK;
    const int e1 = min(e0 + PCHUNK, E_);
    for (int i = e0 + t; i < e1; i += 256) atomicAdd(&hist[dst[i] >> NPB_SHIFT], 1);
    __syncthreads();
    for (int i = t; i < KB_; i += 256) if (hist[i]) gbase[i] = atomicAdd(&bcur[i], hist[i]);
    __syncthreads();
    for (int i = e0 + t; i < e1; i += 256) {
        const int d = dst[i];
        const int b = d >> NPB_SHIFT;
        const int lp = atomicAdd(&lcur[b], 1);
        ebuf[gbase[b] + lp] = src[i] | (etype[i] << 17) | ((d & (NPB - 1)) << 20);
    }
}

// per-bucket node histogram via LDS atomics -> counts[N]
__global__ __launch_bounds__(256) void bnodehist_kernel(
    const int* __restrict__ boffs, const int* __restrict__ ebuf,
    int* __restrict__ counts)
{
    __shared__ int cnt[NPB];
    const int b = blockIdx.x, t = threadIdx.x;
    cnt[t] = 0; cnt[t + 256] = 0;
    __syncthreads();
    const int s0 = boffs[b], s1 = boffs[b + 1];
    for (int i = s0 + t; i < s1; i += 256) atomicAdd(&cnt[ebuf[i] >> 20], 1);
    __syncthreads();
    const int base = b << NPB_SHIFT;
    if (base + t < N_)       counts[base + t]       = cnt[t];
    if (base + t + 256 < N_) counts[base + t + 256] = cnt[t + 256];
}

// ======================= N-element scan for rowptr =======================
__global__ __launch_bounds__(256) void scan1_kernel(
    const int* __restrict__ counts, int* __restrict__ tmp,
    int* __restrict__ blocksum, int n)
{
    __shared__ int sh[256];
    const int t = threadIdx.x;
    const int i = blockIdx.x * 256 + t;
    const int v = (i < n) ? counts[i] : 0;
    sh[t] = v; __syncthreads();
#pragma unroll
    for (int off = 1; off < 256; off <<= 1) {
        const int u = (t >= off) ? sh[t - off] : 0;
        __syncthreads();
        sh[t] += u;
        __syncthreads();
    }
    if (i < n) tmp[i] = sh[t];
    if (t == 255) blocksum[blockIdx.x] = sh[255];
}

__global__ __launch_bounds__(512) void scan2_kernel(
    const int* __restrict__ blocksum, int* __restrict__ offs, int nb)
{
    __shared__ int sh[512];
    const int t = threadIdx.x;
    const int v = (t < nb) ? blocksum[t] : 0;
    sh[t] = v; __syncthreads();
#pragma unroll
    for (int off = 1; off < 512; off <<= 1) {
        const int u = (t >= off) ? sh[t - off] : 0;
        __syncthreads();
        sh[t] += u;
        __syncthreads();
    }
    if (t < nb) offs[t] = sh[t] - v;   // exclusive
}

__global__ __launch_bounds__(256) void scan3_kernel(
    const int* __restrict__ counts, const int* __restrict__ tmp,
    const int* __restrict__ offs, int* __restrict__ rowptr, int n)
{
    const int i = blockIdx.x * 256 + threadIdx.x;
    if (i < n) rowptr[i] = tmp[i] - counts[i] + offs[blockIdx.x];
    if (i == 0) rowptr[n] = E_;
}

// ======================= Stage B: fine scatter (L2-local) =======================
__global__ __launch_bounds__(256) void bscatter_kernel(
    const int* __restrict__ boffs, const int* __restrict__ rowptr,
    const int* __restrict__ ebuf, int* __restrict__ pack)
{
    __shared__ int cur[NPB];
    const int b = blockIdx.x, t = threadIdx.x;
    const int base = b << NPB_SHIFT;
    cur[t]       = (base + t       < N_) ? rowptr[base + t]       : 0;
    cur[t + 256] = (base + t + 256 < N_) ? rowptr[base + t + 256] : 0;
    __syncthreads();
    const int s0 = boffs[b], s1 = boffs[b + 1];
    for (int i = s0 + t; i < s1; i += 256) {
        const int p = ebuf[i];
        const int pos = atomicAdd(&cur[p >> 20], 1);
        pack[pos] = p & 0xFFFFF;   // src | etype<<17
    }
}

// ======================= Needed-set for the pruned layer =======================
// flag srcs of edges into nodes [0,NT_) plus nodes [0,NT_) themselves.
__global__ __launch_bounds__(256) void flagset_kernel(
    const int* __restrict__ rowptr, const int* __restrict__ pack,
    int* __restrict__ flag)
{
    const int lim = rowptr[NT_];   // nodes 0..NT_-1 are buckets 0..7: contiguous prefix
    const int tid = blockIdx.x * 256 + threadIdx.x;
    if (tid < NT_) flag[tid] = 1;
    for (int i = tid; i < lim; i += gridDim.x * 256)
        flag[pack[i] & 0x1FFFF] = 1;
}

__global__ __launch_bounds__(256) void compact_kernel(
    const int* __restrict__ flag, int* __restrict__ nlist, int* __restrict__ cnt)
{
    const int n = blockIdx.x * 256 + threadIdx.x;
    if (n < N_ && flag[n]) nlist[atomicAdd(cnt, 1)] = n;
}

// ======================= Layer 0 fused gather (K = 4) =======================
__global__ __launch_bounds__(256) void gather0_kernel(
    const float* __restrict__ x, const int* __restrict__ rowptr,
    const int* __restrict__ pack, const float* __restrict__ comp,
    const float* __restrict__ V0, const float* __restrict__ loop0,
    const float* __restrict__ bias0,
    float* __restrict__ cs, __half* __restrict__ hout)
{
    __shared__ float hs[8][12];   // [g][0..3]=x_own [4..7]=a0 [8..11]=a1
    __shared__ float cmp[10];
    const int t = threadIdx.x, lane = t & 31, g = t >> 5;
    if (t < 10) cmp[t] = comp[t];
    const int n = blockIdx.x * 8 + g;      // grid exact: N_/8 blocks
    const int k4 = lane & 3, slot = lane >> 2;
    if (lane < 4) hs[g][lane] = x[n * 4 + lane];
    __syncthreads();
    const int beg = rowptr[n], end = rowptr[n + 1];
    float a0 = 0.f, a1 = 0.f;
    for (int e = beg + slot; e < end; e += 8) {
        const int p = pack[e];
        const int s = p & 0x1FFFF, tt = (p >> 17) & 7;
        const float v = x[s * 4 + k4];
        a0 += cmp[tt * 2] * v;
        a1 += cmp[tt * 2 + 1] * v;
    }
    a0 += __shfl_xor(a0, 4);  a1 += __shfl_xor(a1, 4);
    a0 += __shfl_xor(a0, 8);  a1 += __shfl_xor(a1, 8);
    a0 += __shfl_xor(a0, 16); a1 += __shfl_xor(a1, 16);
    if (lane < 4) { hs[g][4 + lane] = a0; hs[g][8 + lane] = a1; }
    __syncthreads();
    float o = bias0[lane];
#pragma unroll
    for (int k = 0; k < 4; ++k) {
        o += hs[g][k] * loop0[k * 32 + lane]
           + hs[g][4 + k] * V0[k * 32 + lane]
           + hs[g][8 + k] * V0[128 + k * 32 + lane];
    }
    const float r = tanhf(o);
    if (n < NT_) cs[n * 128 + lane] = r;
    hout[n * 32 + lane] = __float2half(r);
}

// ======================= Shared gather body (K = 32) =======================
// 4 lanes per edge (8 edges in flight per 32-lane group); fp16 h (self + neighbors).
__device__ __forceinline__ void gather_body(
    int n, int lane, int g,
    const __half* __restrict__ hin, const int* __restrict__ rowptr,
    const int* __restrict__ pack, const float* cmp,
    const float* __restrict__ V, const float* __restrict__ loopW,
    const float* __restrict__ bias,
    float* __restrict__ cs, __half* __restrict__ hout,
    int out_off, int writeH, float hs[8][96])
{
    hs[g][lane] = __half2float(hin[n * 32 + lane]);
    const int beg = rowptr[n], end = rowptr[n + 1];
    const int sg = lane >> 2;   // edge slot 0..7
    const int c  = lane & 3;    // chunk: dims 8c..8c+7
    float a0[8] = {0.f,0.f,0.f,0.f,0.f,0.f,0.f,0.f};
    float a1[8] = {0.f,0.f,0.f,0.f,0.f,0.f,0.f,0.f};
#pragma unroll 2
    for (int e0 = beg; e0 < end; e0 += 8) {
        const int e = e0 + sg;
        const bool ok = e < end;
        const int p = pack[ok ? e : beg];
        const int s = p & 0x1FFFF;
        const int tt = (p >> 17) & 7;
        const float c0 = ok ? cmp[tt * 2]     : 0.f;
        const float c1 = ok ? cmp[tt * 2 + 1] : 0.f;
        const uint4 u = *(const uint4*)(hin + (size_t)s * 32 + c * 8);  // 8 halves
        const __half2* hp = (const __half2*)&u;
#pragma unroll
        for (int k = 0; k < 4; ++k) {
            const float2 f = __half22float2(hp[k]);
            a0[2 * k]     += c0 * f.x;
            a0[2 * k + 1] += c0 * f.y;
            a1[2 * k]     += c1 * f.x;
            a1[2 * k + 1] += c1 * f.y;
        }
    }
#pragma unroll
    for (int k = 0; k < 8; ++k) {
        a0[k] += __shfl_xor(a0[k], 4);
        a0[k] += __shfl_xor(a0[k], 8);
        a0[k] += __shfl_xor(a0[k], 16);
        a1[k] += __shfl_xor(a1[k], 4);
        a1[k] += __shfl_xor(a1[k], 8);
        a1[k] += __shfl_xor(a1[k], 16);
    }
    if (lane < 4) {
#pragma unroll
        for (int k = 0; k < 8; ++k) {
            hs[g][32 + c * 8 + k] = a0[k];
            hs[g][64 + c * 8 + k] = a1[k];
        }
    }
    __builtin_amdgcn_wave_barrier();   // group (32 lanes) is within one wave64
    float o = bias[lane];
#pragma unroll 8
    for (int k = 0; k < 32; ++k) {
        o += hs[g][k] * loopW[k * 32 + lane]
           + hs[g][32 + k] * V[k * 32 + lane]
           + hs[g][64 + k] * V[1024 + k * 32 + lane];
    }
    const float r = tanhf(o);
    if (n < NT_) cs[n * 128 + out_off + lane] = r;
    if (writeH) hout[n * 32 + lane] = __float2half(r);
}

// Full-sweep gather: n = blockIdx*8+g (grid sized exactly; no early exit)
__global__ __launch_bounds__(256) void gather_kernel(
    const __half* __restrict__ hin, const int* __restrict__ rowptr,
    const int* __restrict__ pack, const float* __restrict__ comp,
    const float* __restrict__ V, const float* __restrict__ loopW,
    const float* __restrict__ bias,
    float* __restrict__ cs, __half* __restrict__ hout,
    int out_off, int writeH)
{
    __shared__ float hs[8][96];
    __shared__ float cmp[10];
    const int t = threadIdx.x, lane = t & 31, g = t >> 5;
    if (lane < 10) cmp[lane] = comp[lane];   // every wave writes (benign race)
    __builtin_amdgcn_wave_barrier();
    const int n = blockIdx.x * 8 + g;
    gather_body(n, lane, g, hin, rowptr, pack, cmp, V, loopW, bias,
                cs, hout, out_off, writeH, hs);
}

// Pruned gather over compacted node list (barrier-free -> early exit legal)
__global__ __launch_bounds__(256) void gatherL_kernel(
    const __half* __restrict__ hin, const int* __restrict__ rowptr,
    const int* __restrict__ pack, const float* __restrict__ comp,
    const float* __restrict__ V, const float* __restrict__ loopW,
    const float* __restrict__ bias,
    const int* __restrict__ nlist, const int* __restrict__ cnt,
    float* __restrict__ cs, __half* __restrict__ hout, int out_off)
{
    __shared__ float hs[8][96];
    __shared__ float cmp[10];
    const int t = threadIdx.x, lane = t & 31, g = t >> 5;
    if (lane < 10) cmp[lane] = comp[lane];   // per-wave redundant write
    __builtin_amdgcn_wave_barrier();
    const int idx = blockIdx.x * 8 + g;
    if (idx >= *cnt) return;                 // no barriers below: safe divergence
    const int n = nlist[idx];
    gather_body(n, lane, g, hin, rowptr, pack, cmp, V, loopW, bias,
                cs, hout, out_off, 1, hs);
}

// ======================= MLP head =======================
__global__ __launch_bounds__(256) void transpose_w1_kernel(
    const float* __restrict__ w1, float* __restrict__ w1t)
{
    const int idx = blockIdx.x * 256 + threadIdx.x;
    if (idx >= 128 * 256) return;
    const int j = idx >> 8;
    const int k = idx & 255;
    w1t[k * 128 + j] = w1[idx];
}

__global__ __launch_bounds__(128) void mlp_kernel(
    const float* __restrict__ cs, const float* __restrict__ w1t,
    const float* __restrict__ b1, const float* __restrict__ w2,
    const float* __restrict__ b2, float* __restrict__ out)
{
    __shared__ float feat[256];
    __shared__ float part[2];
    const int p = blockIdx.x;
    const int t = threadIdx.x;
    feat[t]       = cs[p * 128 + t];
    feat[128 + t] = cs[(B_ + p) * 128 + t];
    __syncthreads();
    float acc = b1[t];
#pragma unroll 8
    for (int k = 0; k < 256; ++k) acc += feat[k] * w1t[k * 128 + t];
    const float hid = acc > 0.f ? acc : 0.f;
    float v = w2[t] * hid;
#pragma unroll
    for (int off = 32; off > 0; off >>= 1) v += __shfl_down(v, off, 64);
    if ((t & 63) == 0) part[t >> 6] = v;
    __syncthreads();
    if (t == 0) out[p] = part[0] + part[1] + b2[0];
}

extern "C" void kernel_launch(void* const* d_in, const int* in_sizes, int n_in,
                              void* d_out, int out_size, void* d_ws, size_t ws_size,
                              hipStream_t stream) {
    const float* x      = (const float*)d_in[0];
    const int*   src    = (const int*)d_in[1];
    const int*   dst    = (const int*)d_in[2];
    const int*   etype  = (const int*)d_in[3];
    const float* V0     = (const float*)d_in[4];
    const float* comp0  = (const float*)d_in[5];
    const float* loop0  = (const float*)d_in[6];
    const float* bias0  = (const float*)d_in[7];
    const float* Vs     = (const float*)d_in[8];    // [3,2,32,32]
    const float* comps  = (const float*)d_in[9];    // [3,5,2]
    const float* loops  = (const float*)d_in[10];   // [3,32,32]
    const float* biases = (const float*)d_in[11];   // [3,32]
    const float* w1     = (const float*)d_in[12];   // [128,256]
    const float* b1     = (const float*)d_in[13];
    const float* w2     = (const float*)d_in[14];   // [1,128]
    const float* b2     = (const float*)d_in[15];
    float* out = (float*)d_out;

    // Workspace layout
    float* ws   = (float*)d_ws;
    float* cs   = ws;                          // NT_*128 floats (only target rows)
    float* w1t  = cs + (size_t)NT_ * 128;      // 256*128 floats
    __half* hA  = (__half*)(w1t + 256 * 128);  // N*32 halves
    __half* hB  = hA + (size_t)N_ * 32;        // N*32 halves
    int* ebuf     = (int*)(hB + (size_t)N_ * 32); // E
    int* pack     = ebuf + E_;                 // E
    int* rowptr   = pack + E_;                 // N+1
    int* counts   = rowptr + N_ + 1;           // N
    int* tmp      = counts + N_;               // N
    int* blocksum = tmp + N_;                  // 512
    int* offs     = blocksum + 512;            // 512
    int* bhist    = offs + 512;                // KB_
    int* boffs    = bhist + KB_;               // KB_+1
    int* bcur     = boffs + KB_ + 1;           // KB_
    int* flag     = bcur + KB_;                // N
    int* cnt      = flag + N_;                 // 1  (memset together with flag)
    int* nlist    = cnt + 1;                   // N

    const int gathBlocks = N_ / 8;             // 12500 (exact)
    const int g3Blocks   = NT_ / 8;            // 512 (exact)
    const int scanBlocks = (N_ + 255) / 256;   // 391

    // ---- CSR build (bucketed counting sort by dst) ----
    hipMemsetAsync(bhist, 0, KB_ * sizeof(int), stream);
    bhist_kernel<<<NPBLK, 256, 0, stream>>>(dst, bhist);
    bscan_kernel<<<1, 256, 0, stream>>>(bhist, boffs, bcur);
    partition_kernel<<<NPBLK, 256, 0, stream>>>(src, dst, etype, bcur, ebuf);
    bnodehist_kernel<<<KB_, 256, 0, stream>>>(boffs, ebuf, counts);
    scan1_kernel<<<scanBlocks, 256, 0, stream>>>(counts, tmp, blocksum, N_);
    scan2_kernel<<<1, 512, 0, stream>>>(blocksum, offs, scanBlocks);
    scan3_kernel<<<scanBlocks, 256, 0, stream>>>(counts, tmp, offs, rowptr, N_);
    bscatter_kernel<<<KB_, 256, 0, stream>>>(boffs, rowptr, ebuf, pack);

    // ---- needed-node set for the pruned layer (i=2) ----
    hipMemsetAsync(flag, 0, (size_t)(N_ + 1) * sizeof(int), stream);  // flag + cnt
    flagset_kernel<<<256, 256, 0, stream>>>(rowptr, pack, flag);
    compact_kernel<<<scanBlocks, 256, 0, stream>>>(flag, nlist, cnt);

    transpose_w1_kernel<<<(128 * 256 + 255) / 256, 256, 0, stream>>>(w1, w1t);

    // ---- Layer 0 (full) ----
    gather0_kernel<<<gathBlocks, 256, 0, stream>>>(x, rowptr, pack, comp0, V0, loop0, bias0, cs, hA);

    // ---- Layer 1 (full sweep) : hA -> hB ----
    gather_kernel<<<gathBlocks, 256, 0, stream>>>(
        hA, rowptr, pack, comps + 0, Vs + 0, loops + 0, biases + 0,
        cs, hB, 32, 1);

    // ---- Layer 2 (pruned to needed set) : hB -> hA ----
    gatherL_kernel<<<gathBlocks, 256, 0, stream>>>(
        hB, rowptr, pack, comps + 10, Vs + 2048, loops + 1024, biases + 32,
        nlist, cnt, cs, hA, 64);

    // ---- Layer 3 (targets only: nodes [0,NT_)) : hA -> (no hout) ----
    gather_kernel<<<g3Blocks, 256, 0, stream>>>(
        hA, rowptr, pack, comps + 20, Vs + 4096, loops + 2048, biases + 64,
        cs, hB, 96, 0);

    // ---- MLP head ----
    mlp_kernel<<<B_, 128, 0, stream>>>(cs, w1t, b1, w2, b2, out);
}

// Round 6
// 236.328 us; speedup vs baseline: 3.5895x; 1.0326x over previous
//
#include <hip/hip_runtime.h>
#include <hip/hip_fp16.h>

// Problem constants (match reference)
constexpr int N_  = 100000;   // nodes
constexpr int E_  = 1600000;  // edges
constexpr int B_  = 2048;     // pairs
constexpr int L_  = 4;        // layers
constexpr int NT_ = 2 * B_;   // 4096 target nodes (users+items) read by MLP

constexpr int NPB_SHIFT = 9;                    // 512 nodes per bucket
constexpr int NPB = 1 << NPB_SHIFT;
constexpr int KB_ = (N_ + NPB - 1) / NPB;       // 196 buckets
constexpr int PCHUNK = 8192;                    // edges per partition block
constexpr int NPBLK = (E_ + PCHUNK - 1) / PCHUNK; // 196 blocks

// ======================= Stage A: coarse bucket partition =======================
__global__ __launch_bounds__(256) void bhist_kernel(
    const int* __restrict__ dst, int* __restrict__ bhist)
{
    __shared__ int bh[KB_];
    const int t = threadIdx.x;
    for (int i = t; i < KB_; i += 256) bh[i] = 0;
    __syncthreads();
    const int e0 = blockIdx.x * PCHUNK;
    const int e1 = min(e0 + PCHUNK, E_);
    for (int i = e0 + t; i < e1; i += 256) atomicAdd(&bh[dst[i] >> NPB_SHIFT], 1);
    __syncthreads();
    for (int i = t; i < KB_; i += 256) if (bh[i]) atomicAdd(&bhist[i], bh[i]);
}

// single block: exclusive scan of bucket counts -> boffs, bcur
__global__ __launch_bounds__(256) void bscan_kernel(
    const int* __restrict__ bhist, int* __restrict__ boffs, int* __restrict__ bcur)
{
    __shared__ int sh[256];
    const int t = threadIdx.x;
    const int v = (t < KB_) ? bhist[t] : 0;
    sh[t] = v; __syncthreads();
#pragma unroll
    for (int off = 1; off < 256; off <<= 1) {
        const int u = (t >= off) ? sh[t - off] : 0;
        __syncthreads();
        sh[t] += u;
        __syncthreads();
    }
    if (t < KB_) { const int ex = sh[t] - v; boffs[t] = ex; bcur[t] = ex; }
    if (t == 0) boffs[KB_] = E_;
}

// partition edges into bucket-grouped ebuf; pack = src(17) | etype(3)<<17 | dloc(9)<<20
__global__ __launch_bounds__(256) void partition_kernel(
    const int* __restrict__ src, const int* __restrict__ dst,
    const int* __restrict__ etype, int* __restrict__ bcur, int* __restrict__ ebuf)
{
    __shared__ int hist[KB_];
    __shared__ int gbase[KB_];
    __shared__ int lcur[KB_];
    const int t = threadIdx.x;
    for (int i = t; i < KB_; i += 256) { hist[i] = 0; lcur[i] = 0; }
    __syncthreads();
    const int e0 = blockIdx.x * PCHUNK;
    const int e1 = min(e0 + PCHUNK, E_);
    for (int i = e0 + t; i < e1; i += 256) atomicAdd(&hist[dst[i] >> NPB_SHIFT], 1);
    __syncthreads();
    for (int i = t; i < KB_; i += 256) if (hist[i]) gbase[i] = atomicAdd(&bcur[i], hist[i]);
    __syncthreads();
    for (int i = e0 + t; i < e1; i += 256) {
        const int d = dst[i];
        const int b = d >> NPB_SHIFT;
        const int lp = atomicAdd(&lcur[b], 1);
        ebuf[gbase[b] + lp] = src[i] | (etype[i] << 17) | ((d & (NPB - 1)) << 20);
    }
}

// ======================= Fused per-bucket: hist -> scan -> rowptr -> scatter ====
// Bucket b's edges occupy [boffs[b], boffs[b+1]) and its nodes are contiguous, so
// rowptr[node] = bucket_edge_base + local_exclusive_prefix (no global N-scan needed).
__global__ __launch_bounds__(256) void bfinish_kernel(
    const int* __restrict__ boffs, const int* __restrict__ ebuf,
    int* __restrict__ rowptr, int* __restrict__ pack)
{
    __shared__ int cnt[NPB];    // histogram, later reused as scatter cursors
    __shared__ int sh[256];
    const int b = blockIdx.x, t = threadIdx.x;
    const int s0 = boffs[b], s1 = boffs[b + 1];
    cnt[t] = 0; cnt[t + 256] = 0;
    __syncthreads();
    for (int i = s0 + t; i < s1; i += 256) atomicAdd(&cnt[ebuf[i] >> 20], 1);
    __syncthreads();
    const int v0 = cnt[t], v1 = cnt[t + 256];
    // inclusive scan of lower 256
    sh[t] = v0; __syncthreads();
#pragma unroll
    for (int off = 1; off < 256; off <<= 1) {
        const int u = (t >= off) ? sh[t - off] : 0;
        __syncthreads();
        sh[t] += u;
        __syncthreads();
    }
    const int incA = sh[t];
    const int totA = sh[255];
    __syncthreads();
    // inclusive scan of upper 256
    sh[t] = v1; __syncthreads();
#pragma unroll
    for (int off = 1; off < 256; off <<= 1) {
        const int u = (t >= off) ? sh[t - off] : 0;
        __syncthreads();
        sh[t] += u;
        __syncthreads();
    }
    const int incB = sh[t] + totA;
    const int rp0 = s0 + incA - v0;   // exclusive prefix + bucket base
    const int rp1 = s0 + incB - v1;
    const int base = b << NPB_SHIFT;
    if (base + t < N_)       rowptr[base + t]       = rp0;
    if (base + 256 + t < N_) rowptr[base + 256 + t] = rp1;
    cnt[t] = rp0; cnt[t + 256] = rp1;   // reuse as cursors
    if (b == 0 && t == 0) rowptr[N_] = E_;
    __syncthreads();
    for (int i = s0 + t; i < s1; i += 256) {
        const int p = ebuf[i];
        const int pos = atomicAdd(&cnt[p >> 20], 1);
        pack[pos] = p & 0xFFFFF;   // src | etype<<17
    }
}

// ======================= Needed-set for the pruned layer =======================
__global__ __launch_bounds__(256) void flagset_kernel(
    const int* __restrict__ rowptr, const int* __restrict__ pack,
    int* __restrict__ flag)
{
    const int lim = rowptr[NT_];   // nodes 0..NT_-1 are a contiguous edge prefix
    const int tid = blockIdx.x * 256 + threadIdx.x;
    if (tid < NT_) flag[tid] = 1;
    for (int i = tid; i < lim; i += gridDim.x * 256)
        flag[pack[i] & 0x1FFFF] = 1;
}

__global__ __launch_bounds__(256) void compact_kernel(
    const int* __restrict__ flag, int* __restrict__ nlist, int* __restrict__ cnt)
{
    const int n = blockIdx.x * 256 + threadIdx.x;
    if (n < N_ && flag[n]) nlist[atomicAdd(cnt, 1)] = n;
}

// ======================= Layer 0 fused gather (K = 4) =======================
// 32 lanes per node: 8 edge slots x 4 input dims; pack preloaded lane-parallel.
__global__ __launch_bounds__(256) void gather0_kernel(
    const float* __restrict__ x, const int* __restrict__ rowptr,
    const int* __restrict__ pack, const float* __restrict__ comp,
    const float* __restrict__ V0, const float* __restrict__ loop0,
    const float* __restrict__ bias0,
    float* __restrict__ cs, __half* __restrict__ hout)
{
    __shared__ float hs[8][12];   // [g][0..3]=x_own [4..7]=a0 [8..11]=a1
    __shared__ float cmp[10];
    const int t = threadIdx.x, lane = t & 31, g = t >> 5;
    if (t < 10) cmp[t] = comp[t];
    const int n = blockIdx.x * 8 + g;      // grid exact: N_/8 blocks
    const int k4 = lane & 3, slot = lane >> 2;
    if (lane < 4) hs[g][lane] = x[n * 4 + lane];
    __syncthreads();
    const int beg = rowptr[n], end = rowptr[n + 1];
    const int deg = end - beg;
    const int myp = pack[beg + (lane < deg ? lane : 0)];
    float a0 = 0.f, a1 = 0.f;
    // fast path: first 32 edges, all x-loads issued before consumption
    float xv[4], c0v[4], c1v[4];
#pragma unroll
    for (int q = 0; q < 4; ++q) {
        const int e = q * 8 + slot;        // in [0,32)
        const bool ok = e < deg;
        const int p = __shfl(myp, e, 32);
        const int s = p & 0x1FFFF, tt = (p >> 17) & 7;
        c0v[q] = ok ? cmp[tt * 2]     : 0.f;
        c1v[q] = ok ? cmp[tt * 2 + 1] : 0.f;
        xv[q] = x[s * 4 + k4];
    }
#pragma unroll
    for (int q = 0; q < 4; ++q) { a0 += c0v[q] * xv[q]; a1 += c1v[q] * xv[q]; }
    // rare tail: deg > 32
    for (int e = beg + 32 + slot; e < end; e += 8) {
        const int p = pack[e];
        const int s = p & 0x1FFFF, tt = (p >> 17) & 7;
        const float v = x[s * 4 + k4];
        a0 += cmp[tt * 2] * v;
        a1 += cmp[tt * 2 + 1] * v;
    }
    a0 += __shfl_xor(a0, 4);  a1 += __shfl_xor(a1, 4);
    a0 += __shfl_xor(a0, 8);  a1 += __shfl_xor(a1, 8);
    a0 += __shfl_xor(a0, 16); a1 += __shfl_xor(a1, 16);
    if (lane < 4) { hs[g][4 + lane] = a0; hs[g][8 + lane] = a1; }
    __syncthreads();
    float o = bias0[lane];
#pragma unroll
    for (int k = 0; k < 4; ++k) {
        o += hs[g][k] * loop0[k * 32 + lane]
           + hs[g][4 + k] * V0[k * 32 + lane]
           + hs[g][8 + k] * V0[128 + k * 32 + lane];
    }
    const float r = tanhf(o);
    if (n < NT_) cs[n * 128 + lane] = r;
    hout[n * 32 + lane] = __float2half(r);
}

// ======================= Shared gather body (K = 32) =======================
// 4 lanes per edge (8 edges/chunk); packs preloaded lane-parallel, 4 chunks of
// h-loads issued back-to-back (one latency step) for deg<=32 (99.98% of nodes).
__device__ __forceinline__ void gather_body(
    int n, int lane, int g,
    const __half* __restrict__ hin, const int* __restrict__ rowptr,
    const int* __restrict__ pack, const float* cmp,
    const float* __restrict__ V, const float* __restrict__ loopW,
    const float* __restrict__ bias,
    float* __restrict__ cs, __half* __restrict__ hout,
    int out_off, int writeH, float hs[8][96])
{
    hs[g][lane] = __half2float(hin[n * 32 + lane]);
    const int beg = rowptr[n], end = rowptr[n + 1];
    const int deg = end - beg;
    const int sg = lane >> 2;   // edge slot 0..7
    const int c  = lane & 3;    // dim chunk: dims 8c..8c+7
    const int myp = pack[beg + (lane < deg ? lane : 0)];
    float a0[8] = {0.f,0.f,0.f,0.f,0.f,0.f,0.f,0.f};
    float a1[8] = {0.f,0.f,0.f,0.f,0.f,0.f,0.f,0.f};
    uint4 hv[4];
    float c0v[4], c1v[4];
#pragma unroll
    for (int q = 0; q < 4; ++q) {
        const int e = q * 8 + sg;          // in [0,32)
        const bool ok = e < deg;
        const int p = __shfl(myp, e, 32);
        const int s = p & 0x1FFFF;
        const int tt = (p >> 17) & 7;
        c0v[q] = ok ? cmp[tt * 2]     : 0.f;
        c1v[q] = ok ? cmp[tt * 2 + 1] : 0.f;
        hv[q] = *(const uint4*)(hin + (size_t)s * 32 + c * 8);  // 8 halves
    }
#pragma unroll
    for (int q = 0; q < 4; ++q) {
        const __half2* hp = (const __half2*)&hv[q];
#pragma unroll
        for (int k = 0; k < 4; ++k) {
            const float2 f = __half22float2(hp[k]);
            a0[2 * k]     += c0v[q] * f.x;
            a0[2 * k + 1] += c0v[q] * f.y;
            a1[2 * k]     += c1v[q] * f.x;
            a1[2 * k + 1] += c1v[q] * f.y;
        }
    }
    // rare tail: deg > 32
    for (int e0 = beg + 32; e0 < end; e0 += 8) {
        const int e = e0 + sg;
        const bool ok = e < end;
        const int p = pack[ok ? e : beg];
        const int s = p & 0x1FFFF;
        const int tt = (p >> 17) & 7;
        const float c0 = ok ? cmp[tt * 2]     : 0.f;
        const float c1 = ok ? cmp[tt * 2 + 1] : 0.f;
        const uint4 u = *(const uint4*)(hin + (size_t)s * 32 + c * 8);
        const __half2* hp = (const __half2*)&u;
#pragma unroll
        for (int k = 0; k < 4; ++k) {
            const float2 f = __half22float2(hp[k]);
            a0[2 * k]     += c0 * f.x;
            a0[2 * k + 1] += c0 * f.y;
            a1[2 * k]     += c1 * f.x;
            a1[2 * k + 1] += c1 * f.y;
        }
    }
#pragma unroll
    for (int k = 0; k < 8; ++k) {
        a0[k] += __shfl_xor(a0[k], 4);
        a0[k] += __shfl_xor(a0[k], 8);
        a0[k] += __shfl_xor(a0[k], 16);
        a1[k] += __shfl_xor(a1[k], 4);
        a1[k] += __shfl_xor(a1[k], 8);
        a1[k] += __shfl_xor(a1[k], 16);
    }
    if (lane < 4) {
#pragma unroll
        for (int k = 0; k < 8; ++k) {
            hs[g][32 + c * 8 + k] = a0[k];
            hs[g][64 + c * 8 + k] = a1[k];
        }
    }
    __builtin_amdgcn_wave_barrier();   // group (32 lanes) is within one wave64
    float o = bias[lane];
#pragma unroll 8
    for (int k = 0; k < 32; ++k) {
        o += hs[g][k] * loopW[k * 32 + lane]
           + hs[g][32 + k] * V[k * 32 + lane]
           + hs[g][64 + k] * V[1024 + k * 32 + lane];
    }
    const float r = tanhf(o);
    if (n < NT_) cs[n * 128 + out_off + lane] = r;
    if (writeH) hout[n * 32 + lane] = __float2half(r);
}

// Full-sweep gather: n = blockIdx*8+g (grid sized exactly; no early exit)
__global__ __launch_bounds__(256) void gather_kernel(
    const __half* __restrict__ hin, const int* __restrict__ rowptr,
    const int* __restrict__ pack, const float* __restrict__ comp,
    const float* __restrict__ V, const float* __restrict__ loopW,
    const float* __restrict__ bias,
    float* __restrict__ cs, __half* __restrict__ hout,
    int out_off, int writeH)
{
    __shared__ float hs[8][96];
    __shared__ float cmp[10];
    const int t = threadIdx.x, lane = t & 31, g = t >> 5;
    if (lane < 10) cmp[lane] = comp[lane];   // every wave writes (benign race)
    __builtin_amdgcn_wave_barrier();
    const int n = blockIdx.x * 8 + g;
    gather_body(n, lane, g, hin, rowptr, pack, cmp, V, loopW, bias,
                cs, hout, out_off, writeH, hs);
}

// Pruned gather over compacted node list (barrier-free -> early exit legal)
__global__ __launch_bounds__(256) void gatherL_kernel(
    const __half* __restrict__ hin, const int* __restrict__ rowptr,
    const int* __restrict__ pack, const float* __restrict__ comp,
    const float* __restrict__ V, const float* __restrict__ loopW,
    const float* __restrict__ bias,
    const int* __restrict__ nlist, const int* __restrict__ cnt,
    float* __restrict__ cs, __half* __restrict__ hout, int out_off)
{
    __shared__ float hs[8][96];
    __shared__ float cmp[10];
    const int t = threadIdx.x, lane = t & 31, g = t >> 5;
    if (lane < 10) cmp[lane] = comp[lane];   // per-wave redundant write
    __builtin_amdgcn_wave_barrier();
    const int idx = blockIdx.x * 8 + g;
    if (idx >= *cnt) return;                 // no barriers below: safe divergence
    const int n = nlist[idx];
    gather_body(n, lane, g, hin, rowptr, pack, cmp, V, loopW, bias,
                cs, hout, out_off, 1, hs);
}

// ======================= MLP head =======================
__global__ __launch_bounds__(256) void transpose_w1_kernel(
    const float* __restrict__ w1, float* __restrict__ w1t)
{
    const int idx = blockIdx.x * 256 + threadIdx.x;
    if (idx >= 128 * 256) return;
    const int j = idx >> 8;
    const int k = idx & 255;
    w1t[k * 128 + j] = w1[idx];
}

__global__ __launch_bounds__(128) void mlp_kernel(
    const float* __restrict__ cs, const float* __restrict__ w1t,
    const float* __restrict__ b1, const float* __restrict__ w2,
    const float* __restrict__ b2, float* __restrict__ out)
{
    __shared__ float feat[256];
    __shared__ float part[2];
    const int p = blockIdx.x;
    const int t = threadIdx.x;
    feat[t]       = cs[p * 128 + t];
    feat[128 + t] = cs[(B_ + p) * 128 + t];
    __syncthreads();
    float acc = b1[t];
#pragma unroll 8
    for (int k = 0; k < 256; ++k) acc += feat[k] * w1t[k * 128 + t];
    const float hid = acc > 0.f ? acc : 0.f;
    float v = w2[t] * hid;
#pragma unroll
    for (int off = 32; off > 0; off >>= 1) v += __shfl_down(v, off, 64);
    if ((t & 63) == 0) part[t >> 6] = v;
    __syncthreads();
    if (t == 0) out[p] = part[0] + part[1] + b2[0];
}

extern "C" void kernel_launch(void* const* d_in, const int* in_sizes, int n_in,
                              void* d_out, int out_size, void* d_ws, size_t ws_size,
                              hipStream_t stream) {
    const float* x      = (const float*)d_in[0];
    const int*   src    = (const int*)d_in[1];
    const int*   dst    = (const int*)d_in[2];
    const int*   etype  = (const int*)d_in[3];
    const float* V0     = (const float*)d_in[4];
    const float* comp0  = (const float*)d_in[5];
    const float* loop0  = (const float*)d_in[6];
    const float* bias0  = (const float*)d_in[7];
    const float* Vs     = (const float*)d_in[8];    // [3,2,32,32]
    const float* comps  = (const float*)d_in[9];    // [3,5,2]
    const float* loops  = (const float*)d_in[10];   // [3,32,32]
    const float* biases = (const float*)d_in[11];   // [3,32]
    const float* w1     = (const float*)d_in[12];   // [128,256]
    const float* b1     = (const float*)d_in[13];
    const float* w2     = (const float*)d_in[14];   // [1,128]
    const float* b2     = (const float*)d_in[15];
    float* out = (float*)d_out;

    // Workspace layout
    float* ws   = (float*)d_ws;
    float* cs   = ws;                          // NT_*128 floats (only target rows)
    float* w1t  = cs + (size_t)NT_ * 128;      // 256*128 floats
    __half* hA  = (__half*)(w1t + 256 * 128);  // N*32 halves
    __half* hB  = hA + (size_t)N_ * 32;        // N*32 halves
    int* ebuf     = (int*)(hB + (size_t)N_ * 32); // E
    int* pack     = ebuf + E_;                 // E
    int* rowptr   = pack + E_;                 // N+1
    int* flag     = rowptr + N_ + 1;           // N
    int* cnt      = flag + N_;                 // 1  (memset together with flag)
    int* nlist    = cnt + 1;                   // N
    int* bhist    = nlist + N_;                // KB_
    int* boffs    = bhist + KB_;               // KB_+1
    int* bcur     = boffs + KB_ + 1;           // KB_

    const int gathBlocks = N_ / 8;             // 12500 (exact)
    const int g3Blocks   = NT_ / 8;            // 512 (exact)
    const int scanBlocks = (N_ + 255) / 256;   // 391

    // ---- CSR build (bucketed counting sort by dst) ----
    hipMemsetAsync(bhist, 0, KB_ * sizeof(int), stream);
    bhist_kernel<<<NPBLK, 256, 0, stream>>>(dst, bhist);
    bscan_kernel<<<1, 256, 0, stream>>>(bhist, boffs, bcur);
    partition_kernel<<<NPBLK, 256, 0, stream>>>(src, dst, etype, bcur, ebuf);
    bfinish_kernel<<<KB_, 256, 0, stream>>>(boffs, ebuf, rowptr, pack);

    // ---- needed-node set for the pruned layer (i=2) ----
    hipMemsetAsync(flag, 0, (size_t)(N_ + 1) * sizeof(int), stream);  // flag + cnt
    flagset_kernel<<<256, 256, 0, stream>>>(rowptr, pack, flag);
    compact_kernel<<<scanBlocks, 256, 0, stream>>>(flag, nlist, cnt);

    transpose_w1_kernel<<<(128 * 256 + 255) / 256, 256, 0, stream>>>(w1, w1t);

    // ---- Layer 0 (full) ----
    gather0_kernel<<<gathBlocks, 256, 0, stream>>>(x, rowptr, pack, comp0, V0, loop0, bias0, cs, hA);

    // ---- Layer 1 (full sweep) : hA -> hB ----
    gather_kernel<<<gathBlocks, 256, 0, stream>>>(
        hA, rowptr, pack, comps + 0, Vs + 0, loops + 0, biases + 0,
        cs, hB, 32, 1);

    // ---- Layer 2 (pruned to needed set) : hB -> hA ----
    gatherL_kernel<<<gathBlocks, 256, 0, stream>>>(
        hB, rowptr, pack, comps + 10, Vs + 2048, loops + 1024, biases + 32,
        nlist, cnt, cs, hA, 64);

    // ---- Layer 3 (targets only: nodes [0,NT_)) : hA -> (no hout) ----
    gather_kernel<<<g3Blocks, 256, 0, stream>>>(
        hA, rowptr, pack, comps + 20, Vs + 4096, loops + 2048, biases + 64,
        cs, hB, 96, 0);

    // ---- MLP head ----
    mlp_kernel<<<B_, 128, 0, stream>>>(cs, w1t, b1, w2, b2, out);
}

// Round 7
// 221.207 us; speedup vs baseline: 3.8349x; 1.0684x over previous
//
#include <hip/hip_runtime.h>
#include <hip/hip_fp16.h>

// Problem constants (match reference)
constexpr int N_  = 100000;   // nodes
constexpr int E_  = 1600000;  // edges
constexpr int B_  = 2048;     // pairs
constexpr int L_  = 4;        // layers
constexpr int NT_ = 2 * B_;   // 4096 target nodes (users+items) read by MLP

constexpr int NPB_SHIFT = 9;                    // 512 nodes per bucket
constexpr int NPB = 1 << NPB_SHIFT;
constexpr int KB_ = (N_ + NPB - 1) / NPB;       // 196 buckets
constexpr int PCHUNK = 8192;                    // edges per partition block
constexpr int NPBLK = (E_ + PCHUNK - 1) / PCHUNK; // 196 blocks

// ======================= cls extraction (one-hot argmax) =======================
__global__ __launch_bounds__(256) void cls_kernel(
    const float* __restrict__ x, unsigned char* __restrict__ cls)
{
    const int n = blockIdx.x * 256 + threadIdx.x;
    if (n >= N_) return;
    const float4 v = *(const float4*)(x + n * 4);
    cls[n] = v.y > 0.5f ? 1 : (v.z > 0.5f ? 2 : (v.w > 0.5f ? 3 : 0));
}

// ======================= Stage A: coarse bucket partition =======================
__global__ __launch_bounds__(256) void bhist_kernel(
    const int* __restrict__ dst, int* __restrict__ bhist)
{
    __shared__ int bh[KB_];
    const int t = threadIdx.x;
    for (int i = t; i < KB_; i += 256) bh[i] = 0;
    __syncthreads();
    const int e0 = blockIdx.x * PCHUNK;
    const int e1 = min(e0 + PCHUNK, E_);
    for (int i = e0 + t; i < e1; i += 256) atomicAdd(&bh[dst[i] >> NPB_SHIFT], 1);
    __syncthreads();
    for (int i = t; i < KB_; i += 256) if (bh[i]) atomicAdd(&bhist[i], bh[i]);
}

// single block: exclusive scan of bucket counts -> boffs, bcur
__global__ __launch_bounds__(256) void bscan_kernel(
    const int* __restrict__ bhist, int* __restrict__ boffs, int* __restrict__ bcur)
{
    __shared__ int sh[256];
    const int t = threadIdx.x;
    const int v = (t < KB_) ? bhist[t] : 0;
    sh[t] = v; __syncthreads();
#pragma unroll
    for (int off = 1; off < 256; off <<= 1) {
        const int u = (t >= off) ? sh[t - off] : 0;
        __syncthreads();
        sh[t] += u;
        __syncthreads();
    }
    if (t < KB_) { const int ex = sh[t] - v; boffs[t] = ex; bcur[t] = ex; }
    if (t == 0) boffs[KB_] = E_;
}

// partition edges into bucket-grouped ebuf; pack = src(17) | etype(3)<<17 | dloc(9)<<20
__global__ __launch_bounds__(256) void partition_kernel(
    const int* __restrict__ src, const int* __restrict__ dst,
    const int* __restrict__ etype, int* __restrict__ bcur, int* __restrict__ ebuf)
{
    __shared__ int hist[KB_];
    __shared__ int gbase[KB_];
    __shared__ int lcur[KB_];
    const int t = threadIdx.x;
    for (int i = t; i < KB_; i += 256) { hist[i] = 0; lcur[i] = 0; }
    __syncthreads();
    const int e0 = blockIdx.x * PCHUNK;
    const int e1 = min(e0 + PCHUNK, E_);
    for (int i = e0 + t; i < e1; i += 256) atomicAdd(&hist[dst[i] >> NPB_SHIFT], 1);
    __syncthreads();
    for (int i = t; i < KB_; i += 256) if (hist[i]) gbase[i] = atomicAdd(&bcur[i], hist[i]);
    __syncthreads();
    for (int i = e0 + t; i < e1; i += 256) {
        const int d = dst[i];
        const int b = d >> NPB_SHIFT;
        const int lp = atomicAdd(&lcur[b], 1);
        ebuf[gbase[b] + lp] = src[i] | (etype[i] << 17) | ((d & (NPB - 1)) << 20);
    }
}

// ======== Fused per-bucket: hist -> scan -> rowptr -> scatter -> LAYER 0 ========
// Bucket b's edges occupy [boffs[b], boffs[b+1]); its 512 nodes are contiguous.
// Layer-0 algebra: x one-hot => agg[d] needs only the (relation x class) histogram:
//   A_b[j] = sum_r cnt[r][j]*comp0[r][b];  agg = sum_{b,j} A_b[j]*V0[b,j,:].
__global__ __launch_bounds__(512) void bfinish_kernel(
    const int* __restrict__ boffs, const int* __restrict__ ebuf,
    const unsigned char* __restrict__ cls,
    const float* __restrict__ comp0, const float* __restrict__ V0,
    const float* __restrict__ loop0, const float* __restrict__ bias0,
    int* __restrict__ rowptr, int* __restrict__ pack,
    float* __restrict__ cs, __half* __restrict__ hout)
{
    __shared__ int cnt[NPB];            // degree hist, later scatter cursors
    __shared__ int sh[NPB];             // scan workspace
    __shared__ unsigned int hist[NPB * 20];  // (rel x cls) histogram per node
    __shared__ float sLoop[128], sV0[256], sBias[32], sCmp[10];
    const int b = blockIdx.x, t = threadIdx.x;
    const int s0 = boffs[b], s1 = boffs[b + 1];
    cnt[t] = 0;
    for (int i = t; i < NPB * 20; i += 512) hist[i] = 0u;
    if (t < 128) sLoop[t] = loop0[t];
    if (t < 256) sV0[t]   = V0[t];
    if (t < 32)  sBias[t] = bias0[t];
    if (t < 10)  sCmp[t]  = comp0[t];
    __syncthreads();
    for (int i = s0 + t; i < s1; i += 512) {
        const int p = ebuf[i];
        const int dloc = p >> 20;
        const int et = (p >> 17) & 7;
        const int c = cls[p & 0x1FFFF];
        atomicAdd(&cnt[dloc], 1);
        atomicAdd(&hist[dloc * 20 + et * 4 + c], 1u);
    }
    __syncthreads();
    const int v = cnt[t];
    sh[t] = v; __syncthreads();
#pragma unroll
    for (int off = 1; off < NPB; off <<= 1) {
        const int u = (t >= off) ? sh[t - off] : 0;
        __syncthreads();
        sh[t] += u;
        __syncthreads();
    }
    const int rp = s0 + sh[t] - v;      // exclusive prefix + bucket base
    const int base = b << NPB_SHIFT;
    const int node = base + t;
    if (node < N_) rowptr[node] = rp;
    cnt[t] = rp;                        // reuse as cursor
    if (b == 0 && t == 0) rowptr[N_] = E_;
    __syncthreads();
    for (int i = s0 + t; i < s1; i += 512) {
        const int p = ebuf[i];
        const int pos = atomicAdd(&cnt[p >> 20], 1);
        pack[pos] = p & 0xFFFFF;        // src | etype<<17
    }
    // ---- layer 0 output for this bucket's nodes (hist is stable) ----
    if (node < N_) {
        float A0[4], A1[4];
#pragma unroll
        for (int j = 0; j < 4; ++j) {
            float a0 = 0.f, a1 = 0.f;
#pragma unroll
            for (int r = 0; r < 5; ++r) {
                const float c = (float)hist[t * 20 + r * 4 + j];
                a0 += c * sCmp[r * 2];
                a1 += c * sCmp[r * 2 + 1];
            }
            A0[j] = a0; A1[j] = a1;
        }
        const int myc = cls[node];
        __half hrow[32];
        const bool wcs = node < NT_;
#pragma unroll 8
        for (int d = 0; d < 32; ++d) {
            float o = sBias[d] + sLoop[myc * 32 + d];
#pragma unroll
            for (int j = 0; j < 4; ++j)
                o += A0[j] * sV0[j * 32 + d] + A1[j] * sV0[128 + j * 32 + d];
            const float r = tanhf(o);
            hrow[d] = __float2half(r);
            if (wcs) cs[node * 128 + d] = r;
        }
        uint4* dst4 = (uint4*)(hout + (size_t)node * 32);
        const uint4* src4 = (const uint4*)hrow;
        dst4[0] = src4[0]; dst4[1] = src4[1]; dst4[2] = src4[2]; dst4[3] = src4[3];
    }
}

// ======================= Needed-set for the pruned layer =======================
__global__ __launch_bounds__(256) void flagset_kernel(
    const int* __restrict__ rowptr, const int* __restrict__ pack,
    int* __restrict__ flag)
{
    const int lim = rowptr[NT_];   // nodes 0..NT_-1 are a contiguous edge prefix
    const int tid = blockIdx.x * 256 + threadIdx.x;
    if (tid < NT_) flag[tid] = 1;
    for (int i = tid; i < lim; i += gridDim.x * 256)
        flag[pack[i] & 0x1FFFF] = 1;
}

__global__ __launch_bounds__(256) void compact_kernel(
    const int* __restrict__ flag, int* __restrict__ nlist, int* __restrict__ cnt)
{
    const int n = blockIdx.x * 256 + threadIdx.x;
    if (n < N_ && flag[n]) nlist[atomicAdd(cnt, 1)] = n;
}

// ======================= Shared gather body (K = 32) =======================
// 4 lanes per edge (8 edges in flight per 32-lane group); fp16 h (self + neighbors).
__device__ __forceinline__ void gather_body(
    int n, int lane, int g,
    const __half* __restrict__ hin, const int* __restrict__ rowptr,
    const int* __restrict__ pack, const float* cmp,
    const float* __restrict__ V, const float* __restrict__ loopW,
    const float* __restrict__ bias,
    float* __restrict__ cs, __half* __restrict__ hout,
    int out_off, int writeH, float hs[8][96])
{
    hs[g][lane] = __half2float(hin[n * 32 + lane]);
    const int beg = rowptr[n], end = rowptr[n + 1];
    const int sg = lane >> 2;   // edge slot 0..7
    const int c  = lane & 3;    // chunk: dims 8c..8c+7
    float a0[8] = {0.f,0.f,0.f,0.f,0.f,0.f,0.f,0.f};
    float a1[8] = {0.f,0.f,0.f,0.f,0.f,0.f,0.f,0.f};
#pragma unroll 2
    for (int e0 = beg; e0 < end; e0 += 8) {
        const int e = e0 + sg;
        const bool ok = e < end;
        const int p = pack[ok ? e : beg];
        const int s = p & 0x1FFFF;
        const int tt = (p >> 17) & 7;
        const float c0 = ok ? cmp[tt * 2]     : 0.f;
        const float c1 = ok ? cmp[tt * 2 + 1] : 0.f;
        const uint4 u = *(const uint4*)(hin + (size_t)s * 32 + c * 8);  // 8 halves
        const __half2* hp = (const __half2*)&u;
#pragma unroll
        for (int k = 0; k < 4; ++k) {
            const float2 f = __half22float2(hp[k]);
            a0[2 * k]     += c0 * f.x;
            a0[2 * k + 1] += c0 * f.y;
            a1[2 * k]     += c1 * f.x;
            a1[2 * k + 1] += c1 * f.y;
        }
    }
#pragma unroll
    for (int k = 0; k < 8; ++k) {
        a0[k] += __shfl_xor(a0[k], 4);
        a0[k] += __shfl_xor(a0[k], 8);
        a0[k] += __shfl_xor(a0[k], 16);
        a1[k] += __shfl_xor(a1[k], 4);
        a1[k] += __shfl_xor(a1[k], 8);
        a1[k] += __shfl_xor(a1[k], 16);
    }
    if (lane < 4) {
#pragma unroll
        for (int k = 0; k < 8; ++k) {
            hs[g][32 + c * 8 + k] = a0[k];
            hs[g][64 + c * 8 + k] = a1[k];
        }
    }
    __builtin_amdgcn_wave_barrier();   // group (32 lanes) is within one wave64
    float o = bias[lane];
#pragma unroll 8
    for (int k = 0; k < 32; ++k) {
        o += hs[g][k] * loopW[k * 32 + lane]
           + hs[g][32 + k] * V[k * 32 + lane]
           + hs[g][64 + k] * V[1024 + k * 32 + lane];
    }
    const float r = tanhf(o);
    if (n < NT_) cs[n * 128 + out_off + lane] = r;
    if (writeH) hout[n * 32 + lane] = __float2half(r);
}

// Full-sweep gather: n = blockIdx*8+g (grid sized exactly; no early exit)
__global__ __launch_bounds__(256) void gather_kernel(
    const __half* __restrict__ hin, const int* __restrict__ rowptr,
    const int* __restrict__ pack, const float* __restrict__ comp,
    const float* __restrict__ V, const float* __restrict__ loopW,
    const float* __restrict__ bias,
    float* __restrict__ cs, __half* __restrict__ hout,
    int out_off, int writeH)
{
    __shared__ float hs[8][96];
    __shared__ float cmp[10];
    const int t = threadIdx.x, lane = t & 31, g = t >> 5;
    if (lane < 10) cmp[lane] = comp[lane];   // every wave writes (benign race)
    __builtin_amdgcn_wave_barrier();
    const int n = blockIdx.x * 8 + g;
    gather_body(n, lane, g, hin, rowptr, pack, cmp, V, loopW, bias,
                cs, hout, out_off, writeH, hs);
}

// Pruned gather over compacted node list (barrier-free -> early exit legal)
__global__ __launch_bounds__(256) void gatherL_kernel(
    const __half* __restrict__ hin, const int* __restrict__ rowptr,
    const int* __restrict__ pack, const float* __restrict__ comp,
    const float* __restrict__ V, const float* __restrict__ loopW,
    const float* __restrict__ bias,
    const int* __restrict__ nlist, const int* __restrict__ cnt,
    float* __restrict__ cs, __half* __restrict__ hout, int out_off)
{
    __shared__ float hs[8][96];
    __shared__ float cmp[10];
    const int t = threadIdx.x, lane = t & 31, g = t >> 5;
    if (lane < 10) cmp[lane] = comp[lane];   // per-wave redundant write
    __builtin_amdgcn_wave_barrier();
    const int idx = blockIdx.x * 8 + g;
    if (idx >= *cnt) return;                 // no barriers below: safe divergence
    const int n = nlist[idx];
    gather_body(n, lane, g, hin, rowptr, pack, cmp, V, loopW, bias,
                cs, hout, out_off, 1, hs);
}

// ======================= MLP head =======================
__global__ __launch_bounds__(256) void transpose_w1_kernel(
    const float* __restrict__ w1, float* __restrict__ w1t)
{
    const int idx = blockIdx.x * 256 + threadIdx.x;
    if (idx >= 128 * 256) return;
    const int j = idx >> 8;
    const int k = idx & 255;
    w1t[k * 128 + j] = w1[idx];
}

__global__ __launch_bounds__(128) void mlp_kernel(
    const float* __restrict__ cs, const float* __restrict__ w1t,
    const float* __restrict__ b1, const float* __restrict__ w2,
    const float* __restrict__ b2, float* __restrict__ out)
{
    __shared__ float feat[256];
    __shared__ float part[2];
    const int p = blockIdx.x;
    const int t = threadIdx.x;
    feat[t]       = cs[p * 128 + t];
    feat[128 + t] = cs[(B_ + p) * 128 + t];
    __syncthreads();
    float acc = b1[t];
#pragma unroll 8
    for (int k = 0; k < 256; ++k) acc += feat[k] * w1t[k * 128 + t];
    const float hid = acc > 0.f ? acc : 0.f;
    float v = w2[t] * hid;
#pragma unroll
    for (int off = 32; off > 0; off >>= 1) v += __shfl_down(v, off, 64);
    if ((t & 63) == 0) part[t >> 6] = v;
    __syncthreads();
    if (t == 0) out[p] = part[0] + part[1] + b2[0];
}

extern "C" void kernel_launch(void* const* d_in, const int* in_sizes, int n_in,
                              void* d_out, int out_size, void* d_ws, size_t ws_size,
                              hipStream_t stream) {
    const float* x      = (const float*)d_in[0];
    const int*   src    = (const int*)d_in[1];
    const int*   dst    = (const int*)d_in[2];
    const int*   etype  = (const int*)d_in[3];
    const float* V0     = (const float*)d_in[4];
    const float* comp0  = (const float*)d_in[5];
    const float* loop0  = (const float*)d_in[6];
    const float* bias0  = (const float*)d_in[7];
    const float* Vs     = (const float*)d_in[8];    // [3,2,32,32]
    const float* comps  = (const float*)d_in[9];    // [3,5,2]
    const float* loops  = (const float*)d_in[10];   // [3,32,32]
    const float* biases = (const float*)d_in[11];   // [3,32]
    const float* w1     = (const float*)d_in[12];   // [128,256]
    const float* b1     = (const float*)d_in[13];
    const float* w2     = (const float*)d_in[14];   // [1,128]
    const float* b2     = (const float*)d_in[15];
    float* out = (float*)d_out;

    // Workspace layout
    float* ws   = (float*)d_ws;
    float* cs   = ws;                          // NT_*128 floats (only target rows)
    float* w1t  = cs + (size_t)NT_ * 128;      // 256*128 floats
    __half* hA  = (__half*)(w1t + 256 * 128);  // N*32 halves
    __half* hB  = hA + (size_t)N_ * 32;        // N*32 halves
    int* ebuf     = (int*)(hB + (size_t)N_ * 32); // E
    int* pack     = ebuf + E_;                 // E
    int* rowptr   = pack + E_;                 // N+1
    int* flag     = rowptr + N_ + 1;           // N
    int* cnt      = flag + N_;                 // 1  (memset together with flag)
    int* nlist    = cnt + 1;                   // N
    int* bhist    = nlist + N_;                // KB_
    int* boffs    = bhist + KB_;               // KB_+1
    int* bcur     = boffs + KB_ + 1;           // KB_
    unsigned char* cls = (unsigned char*)(bcur + KB_);  // N bytes

    const int gathBlocks = N_ / 8;             // 12500 (exact)
    const int g3Blocks   = NT_ / 8;            // 512 (exact)
    const int scanBlocks = (N_ + 255) / 256;   // 391

    // ---- cls extraction (needed by bfinish) ----
    cls_kernel<<<scanBlocks, 256, 0, stream>>>(x, cls);

    // ---- CSR build (bucketed counting sort by dst) + fused layer 0 ----
    hipMemsetAsync(bhist, 0, KB_ * sizeof(int), stream);
    bhist_kernel<<<NPBLK, 256, 0, stream>>>(dst, bhist);
    bscan_kernel<<<1, 256, 0, stream>>>(bhist, boffs, bcur);
    partition_kernel<<<NPBLK, 256, 0, stream>>>(src, dst, etype, bcur, ebuf);
    bfinish_kernel<<<KB_, 512, 0, stream>>>(boffs, ebuf, cls, comp0, V0, loop0, bias0,
                                            rowptr, pack, cs, hA);

    // ---- needed-node set for the pruned layer (i=2) ----
    hipMemsetAsync(flag, 0, (size_t)(N_ + 1) * sizeof(int), stream);  // flag + cnt
    flagset_kernel<<<256, 256, 0, stream>>>(rowptr, pack, flag);
    compact_kernel<<<scanBlocks, 256, 0, stream>>>(flag, nlist, cnt);

    transpose_w1_kernel<<<(128 * 256 + 255) / 256, 256, 0, stream>>>(w1, w1t);

    // ---- Layer 1 (full sweep) : hA -> hB ----
    gather_kernel<<<gathBlocks, 256, 0, stream>>>(
        hA, rowptr, pack, comps + 0, Vs + 0, loops + 0, biases + 0,
        cs, hB, 32, 1);

    // ---- Layer 2 (pruned to needed set) : hB -> hA ----
    gatherL_kernel<<<gathBlocks, 256, 0, stream>>>(
        hB, rowptr, pack, comps + 10, Vs + 2048, loops + 1024, biases + 32,
        nlist, cnt, cs, hA, 64);

    // ---- Layer 3 (targets only: nodes [0,NT_)) : hA -> (no hout) ----
    gather_kernel<<<g3Blocks, 256, 0, stream>>>(
        hA, rowptr, pack, comps + 20, Vs + 4096, loops + 2048, biases + 64,
        cs, hB, 96, 0);

    // ---- MLP head ----
    mlp_kernel<<<B_, 128, 0, stream>>>(cs, w1t, b1, w2, b2, out);
}

// Round 8
// 187.214 us; speedup vs baseline: 4.5312x; 1.1816x over previous
//
#include <hip/hip_runtime.h>
#include <hip/hip_fp16.h>

// Problem constants (match reference)
constexpr int N_  = 100000;   // nodes
constexpr int E_  = 1600000;  // edges
constexpr int B_  = 2048;     // pairs
constexpr int NT_ = 2 * B_;   // 4096 target nodes (users+items) read by MLP

constexpr int NPB_SHIFT = 9;                    // 512 nodes per bucket
constexpr int NPB = 1 << NPB_SHIFT;
constexpr int KB_ = (N_ + NPB - 1) / NPB;       // 196 buckets
constexpr int CAP_ = 9216;                      // per-bucket capacity (mean 8192, 11 sigma)
constexpr int PCHUNK = 8192;                    // edges per partition block
constexpr int NPBLK = (E_ + PCHUNK - 1) / PCHUNK; // 196 blocks

// ================= init: cls + zero(flag,cnt,bcur) + transpose w1 =================
__global__ __launch_bounds__(256) void init_kernel(
    const float* __restrict__ x, const float* __restrict__ w1,
    unsigned char* __restrict__ cls, int* __restrict__ flag,
    int* __restrict__ cnt, int* __restrict__ bcur, float* __restrict__ w1t)
{
    const int b = blockIdx.x, t = threadIdx.x;
    if (b < 391) {
        const int n = b * 256 + t;
        if (n < N_) {
            const float4 v = *(const float4*)(x + n * 4);
            cls[n] = v.y > 0.5f ? 1 : (v.z > 0.5f ? 2 : (v.w > 0.5f ? 3 : 0));
            flag[n] = 0;
        }
        if (b == 0 && t == 0) *cnt = 0;
    } else if (b < 519) {
        const int idx = (b - 391) * 256 + t;   // < 32768
        const int j = idx >> 8, k = idx & 255;
        w1t[k * 128 + j] = w1[idx];
    } else {
        if (t < KB_) bcur[t] = 0;
    }
}

// ========== partition: edges -> CAP-strided bucket regions (no pre-scan) ==========
// pack word = src(17) | etype(3)<<17 | dloc(9)<<20
__global__ __launch_bounds__(256) void partition_kernel(
    const int* __restrict__ src, const int* __restrict__ dst,
    const int* __restrict__ etype, int* __restrict__ bcur, int* __restrict__ ebuf)
{
    __shared__ int hist[KB_];
    __shared__ int gbase[KB_];
    __shared__ int lcur[KB_];
    const int t = threadIdx.x;
    for (int i = t; i < KB_; i += 256) { hist[i] = 0; lcur[i] = 0; }
    __syncthreads();
    const int e0 = blockIdx.x * PCHUNK;
    const int e1 = min(e0 + PCHUNK, E_);
    for (int i = e0 + t; i < e1; i += 256) atomicAdd(&hist[dst[i] >> NPB_SHIFT], 1);
    __syncthreads();
    for (int i = t; i < KB_; i += 256) if (hist[i]) gbase[i] = atomicAdd(&bcur[i], hist[i]);
    __syncthreads();
    for (int i = e0 + t; i < e1; i += 256) {
        const int d = dst[i];
        const int b = d >> NPB_SHIFT;
        const int lp = atomicAdd(&lcur[b], 1);
        ebuf[(size_t)b * CAP_ + gbase[b] + lp] = src[i] | (etype[i] << 17) | ((d & (NPB - 1)) << 20);
    }
}

// single block: exclusive scan of bucket counts (in bcur) -> dense bases boffs
__global__ __launch_bounds__(256) void bscan_kernel(
    const int* __restrict__ bcur, int* __restrict__ boffs)
{
    __shared__ int sh[256];
    const int t = threadIdx.x;
    const int v = (t < KB_) ? bcur[t] : 0;
    sh[t] = v; __syncthreads();
#pragma unroll
    for (int off = 1; off < 256; off <<= 1) {
        const int u = (t >= off) ? sh[t - off] : 0;
        __syncthreads();
        sh[t] += u;
        __syncthreads();
    }
    if (t < KB_) boffs[t] = sh[t] - v;   // exclusive
    if (t == 0) boffs[KB_] = E_;
}

// ======== fused per-bucket: hist -> scan -> rowptr -> dense scatter -> LAYER 0 ====
// Layer-0 algebra: x one-hot => agg[d] needs only the (relation x class) histogram.
__global__ __launch_bounds__(512) void bfinish_kernel(
    const int* __restrict__ bcur, const int* __restrict__ boffs,
    const int* __restrict__ ebuf, const unsigned char* __restrict__ cls,
    const float* __restrict__ comp0, const float* __restrict__ V0,
    const float* __restrict__ loop0, const float* __restrict__ bias0,
    int* __restrict__ rowptr, int* __restrict__ pack,
    float* __restrict__ cs, __half* __restrict__ hout)
{
    __shared__ int cnt[NPB];            // degree hist, later scatter cursors
    __shared__ int sh[NPB];             // scan workspace
    __shared__ unsigned int hist[NPB * 20];  // (rel x cls) histogram per node
    __shared__ float sLoop[128], sV0[256], sBias[32], sCmp[10];
    const int b = blockIdx.x, t = threadIdx.x;
    const int s0 = b * CAP_;
    const int s1 = s0 + bcur[b];        // bucket edge count
    const int db = boffs[b];            // dense base for pack/rowptr
    cnt[t] = 0;
    for (int i = t; i < NPB * 20; i += 512) hist[i] = 0u;
    if (t < 128) sLoop[t] = loop0[t];
    if (t < 256) sV0[t]   = V0[t];
    if (t < 32)  sBias[t] = bias0[t];
    if (t < 10)  sCmp[t]  = comp0[t];
    __syncthreads();
    for (int i = s0 + t; i < s1; i += 512) {
        const int p = ebuf[i];
        const int dloc = p >> 20;
        const int et = (p >> 17) & 7;
        const int c = cls[p & 0x1FFFF];
        atomicAdd(&cnt[dloc], 1);
        atomicAdd(&hist[dloc * 20 + et * 4 + c], 1u);
    }
    __syncthreads();
    const int v = cnt[t];
    sh[t] = v; __syncthreads();
#pragma unroll
    for (int off = 1; off < NPB; off <<= 1) {
        const int u = (t >= off) ? sh[t - off] : 0;
        __syncthreads();
        sh[t] += u;
        __syncthreads();
    }
    const int rp = db + sh[t] - v;      // dense exclusive prefix + bucket base
    const int node = (b << NPB_SHIFT) + t;
    if (node < N_) rowptr[node] = rp;
    cnt[t] = rp;                        // reuse as cursor
    if (b == 0 && t == 0) rowptr[N_] = E_;
    __syncthreads();
    for (int i = s0 + t; i < s1; i += 512) {
        const int p = ebuf[i];
        const int pos = atomicAdd(&cnt[p >> 20], 1);
        pack[pos] = p & 0xFFFFF;        // src | etype<<17
    }
    // ---- layer 0 output for this bucket's nodes (hist is stable) ----
    if (node < N_) {
        float A0[4], A1[4];
#pragma unroll
        for (int j = 0; j < 4; ++j) {
            float a0 = 0.f, a1 = 0.f;
#pragma unroll
            for (int r = 0; r < 5; ++r) {
                const float c = (float)hist[t * 20 + r * 4 + j];
                a0 += c * sCmp[r * 2];
                a1 += c * sCmp[r * 2 + 1];
            }
            A0[j] = a0; A1[j] = a1;
        }
        const int myc = cls[node];
        __half hrow[32];
        const bool wcs = node < NT_;
#pragma unroll 8
        for (int d = 0; d < 32; ++d) {
            float o = sBias[d] + sLoop[myc * 32 + d];
#pragma unroll
            for (int j = 0; j < 4; ++j)
                o += A0[j] * sV0[j * 32 + d] + A1[j] * sV0[128 + j * 32 + d];
            const float r = tanhf(o);
            hrow[d] = __float2half(r);
            if (wcs) cs[node * 128 + d] = r;
        }
        uint4* dst4 = (uint4*)(hout + (size_t)node * 32);
        const uint4* src4 = (const uint4*)hrow;
        dst4[0] = src4[0]; dst4[1] = src4[1]; dst4[2] = src4[2]; dst4[3] = src4[3];
    }
}

// ============ fused flag+compact: needed set for the pruned layer (i=2) ============
__global__ __launch_bounds__(256) void flagcompact_kernel(
    const int* __restrict__ rowptr, const int* __restrict__ pack,
    int* __restrict__ flag, int* __restrict__ cnt, int* __restrict__ nlist)
{
    const int lim = rowptr[NT_];   // nodes [0,NT_) are a contiguous edge prefix
    const int tid = blockIdx.x * 256 + threadIdx.x;
    if (tid < NT_) nlist[atomicAdd(cnt, 1)] = tid;          // targets (unique)
    const int stride = gridDim.x * 256;
    for (int i = tid; i < lim; i += stride) {
        const int s = pack[i] & 0x1FFFF;
        if (s >= NT_ && atomicExch(&flag[s], 1) == 0)       // dedup append
            nlist[atomicAdd(cnt, 1)] = s;
    }
}

// ======================= shared gather body (K = 32) =======================
// 4 lanes per edge; deg<=32 fast path: 4 independent pack loads then 4 h loads,
// all in flight before any FMA (no shfl in the address chain). Returns r[lane].
__device__ __forceinline__ void acc_chunk(
    const uint4& v, int pq, bool ok, const float* cmp, float* a0, float* a1)
{
    const int tt = (pq >> 17) & 7;
    const float c0 = ok ? cmp[tt * 2]     : 0.f;
    const float c1 = ok ? cmp[tt * 2 + 1] : 0.f;
    const __half2* hp = (const __half2*)&v;
#pragma unroll
    for (int k = 0; k < 4; ++k) {
        const float2 f = __half22float2(hp[k]);
        a0[2 * k]     += c0 * f.x;
        a0[2 * k + 1] += c0 * f.y;
        a1[2 * k]     += c1 * f.x;
        a1[2 * k + 1] += c1 * f.y;
    }
}

__device__ __forceinline__ float gather_body(
    int n, int lane, int g,
    const __half* __restrict__ hin, const int* __restrict__ rowptr,
    const int* __restrict__ pack, const float* cmp,
    const float* __restrict__ V, const float* __restrict__ loopW,
    const float* __restrict__ bias, float (*hs)[96])
{
    hs[g][lane] = __half2float(hin[n * 32 + lane]);
    const int beg = rowptr[n], end = rowptr[n + 1];
    const int sg = lane >> 2;   // edge slot 0..7
    const int c  = lane & 31 & 3;   // dim chunk: dims 8c..8c+7
    const int i0 = beg + sg, i1 = i0 + 8, i2 = i0 + 16, i3 = i0 + 24;
    // 4 independent pack loads
    const int p0 = pack[i0 < end ? i0 : beg];
    const int p1 = pack[i1 < end ? i1 : beg];
    const int p2 = pack[i2 < end ? i2 : beg];
    const int p3 = pack[i3 < end ? i3 : beg];
    // 4 h loads, each dependent only on its own pack word
    const uint4 v0 = *(const uint4*)(hin + (size_t)(p0 & 0x1FFFF) * 32 + c * 8);
    const uint4 v1 = *(const uint4*)(hin + (size_t)(p1 & 0x1FFFF) * 32 + c * 8);
    const uint4 v2 = *(const uint4*)(hin + (size_t)(p2 & 0x1FFFF) * 32 + c * 8);
    const uint4 v3 = *(const uint4*)(hin + (size_t)(p3 & 0x1FFFF) * 32 + c * 8);
    float a0[8] = {0.f,0.f,0.f,0.f,0.f,0.f,0.f,0.f};
    float a1[8] = {0.f,0.f,0.f,0.f,0.f,0.f,0.f,0.f};
    acc_chunk(v0, p0, i0 < end, cmp, a0, a1);
    acc_chunk(v1, p1, i1 < end, cmp, a0, a1);
    acc_chunk(v2, p2, i2 < end, cmp, a0, a1);
    acc_chunk(v3, p3, i3 < end, cmp, a0, a1);
    // rare tail: deg > 32
    for (int e0 = beg + 32; e0 < end; e0 += 8) {
        const int e = e0 + sg;
        const bool ok = e < end;
        const int p = pack[ok ? e : beg];
        const uint4 u = *(const uint4*)(hin + (size_t)(p & 0x1FFFF) * 32 + c * 8);
        acc_chunk(u, p, ok, cmp, a0, a1);
    }
#pragma unroll
    for (int k = 0; k < 8; ++k) {
        a0[k] += __shfl_xor(a0[k], 4);
        a0[k] += __shfl_xor(a0[k], 8);
        a0[k] += __shfl_xor(a0[k], 16);
        a1[k] += __shfl_xor(a1[k], 4);
        a1[k] += __shfl_xor(a1[k], 8);
        a1[k] += __shfl_xor(a1[k], 16);
    }
    if (lane < 4) {
#pragma unroll
        for (int k = 0; k < 8; ++k) {
            hs[g][32 + c * 8 + k] = a0[k];
            hs[g][64 + c * 8 + k] = a1[k];
        }
    }
    __builtin_amdgcn_wave_barrier();   // 32-lane group is within one wave64
    float o = bias[lane];
#pragma unroll 8
    for (int k = 0; k < 32; ++k) {
        o += hs[g][k] * loopW[k * 32 + lane]
           + hs[g][32 + k] * V[k * 32 + lane]
           + hs[g][64 + k] * V[1024 + k * 32 + lane];
    }
    return tanhf(o);
}

// Full-sweep gather (layer 1): n = blockIdx*8+g, grid exact
__global__ __launch_bounds__(256) void gather_kernel(
    const __half* __restrict__ hin, const int* __restrict__ rowptr,
    const int* __restrict__ pack, const float* __restrict__ comp,
    const float* __restrict__ V, const float* __restrict__ loopW,
    const float* __restrict__ bias,
    float* __restrict__ cs, __half* __restrict__ hout, int out_off)
{
    __shared__ float hs[8][96];
    __shared__ float cmp[10];
    const int t = threadIdx.x, lane = t & 31, g = t >> 5;
    if (lane < 10) cmp[lane] = comp[lane];   // every wave writes (benign)
    __builtin_amdgcn_wave_barrier();
    const int n = blockIdx.x * 8 + g;
    const float r = gather_body(n, lane, g, hin, rowptr, pack, cmp, V, loopW, bias, hs);
    if (n < NT_) cs[n * 128 + out_off + lane] = r;
    hout[n * 32 + lane] = __float2half(r);
}

// Pruned gather over compacted node list (barrier-free -> early exit legal)
__global__ __launch_bounds__(256) void gatherL_kernel(
    const __half* __restrict__ hin, const int* __restrict__ rowptr,
    const int* __restrict__ pack, const float* __restrict__ comp,
    const float* __restrict__ V, const float* __restrict__ loopW,
    const float* __restrict__ bias,
    const int* __restrict__ nlist, const int* __restrict__ cnt,
    float* __restrict__ cs, __half* __restrict__ hout, int out_off)
{
    __shared__ float hs[8][96];
    __shared__ float cmp[10];
    const int t = threadIdx.x, lane = t & 31, g = t >> 5;
    if (lane < 10) cmp[lane] = comp[lane];
    __builtin_amdgcn_wave_barrier();
    const int idx = blockIdx.x * 8 + g;
    if (idx >= *cnt) return;                 // no barriers below: safe divergence
    const int n = nlist[idx];
    const float r = gather_body(n, lane, g, hin, rowptr, pack, cmp, V, loopW, bias, hs);
    if (n < NT_) cs[n * 128 + out_off + lane] = r;
    hout[n * 32 + lane] = __float2half(r);
}

// ================= MLP head with fused layer-3 gather (targets only) =============
// wave 0 (threads 0..63): gather layer-3 rows for nodes p and B_+p into feat[96..127].
// wave 1 (threads 64..127): load cs slots 0..95 for both nodes.
__global__ __launch_bounds__(128) void mlp_kernel(
    const __half* __restrict__ hin, const int* __restrict__ rowptr,
    const int* __restrict__ pack, const float* __restrict__ comp,
    const float* __restrict__ V, const float* __restrict__ loopW,
    const float* __restrict__ bias,
    const float* __restrict__ cs, const float* __restrict__ w1t,
    const float* __restrict__ b1, const float* __restrict__ w2,
    const float* __restrict__ b2, float* __restrict__ out)
{
    __shared__ float feat[256];
    __shared__ float hs[2][96];
    __shared__ float cmp[10];
    __shared__ float part[2];
    const int p = blockIdx.x, t = threadIdx.x;
    if (t < 10) cmp[t] = comp[t];            // wave 0, before its gather
    if (t < 64) {
        const int g = t >> 5, lane = t & 31;
        const int n = g ? (B_ + p) : p;
        const float r = gather_body(n, lane, g, hin, rowptr, pack, cmp, V, loopW, bias, hs);
        feat[g * 128 + 96 + lane] = r;
    } else {
        const int i = t - 64;                // 0..63
        for (int j = i; j < 96; j += 64) {
            feat[j]       = cs[p * 128 + j];
            feat[128 + j] = cs[(B_ + p) * 128 + j];
        }
    }
    __syncthreads();
    float acc = b1[t];
#pragma unroll 8
    for (int k = 0; k < 256; ++k) acc += feat[k] * w1t[k * 128 + t];
    const float hid = acc > 0.f ? acc : 0.f;
    float v = w2[t] * hid;
#pragma unroll
    for (int off = 32; off > 0; off >>= 1) v += __shfl_down(v, off, 64);
    if ((t & 63) == 0) part[t >> 6] = v;
    __syncthreads();
    if (t == 0) out[p] = part[0] + part[1] + b2[0];
}

extern "C" void kernel_launch(void* const* d_in, const int* in_sizes, int n_in,
                              void* d_out, int out_size, void* d_ws, size_t ws_size,
                              hipStream_t stream) {
    const float* x      = (const float*)d_in[0];
    const int*   src    = (const int*)d_in[1];
    const int*   dst    = (const int*)d_in[2];
    const int*   etype  = (const int*)d_in[3];
    const float* V0     = (const float*)d_in[4];
    const float* comp0  = (const float*)d_in[5];
    const float* loop0  = (const float*)d_in[6];
    const float* bias0  = (const float*)d_in[7];
    const float* Vs     = (const float*)d_in[8];    // [3,2,32,32]
    const float* comps  = (const float*)d_in[9];    // [3,5,2]
    const float* loops  = (const float*)d_in[10];   // [3,32,32]
    const float* biases = (const float*)d_in[11];   // [3,32]
    const float* w1     = (const float*)d_in[12];   // [128,256]
    const float* b1     = (const float*)d_in[13];
    const float* w2     = (const float*)d_in[14];   // [1,128]
    const float* b2     = (const float*)d_in[15];
    float* out = (float*)d_out;

    // Workspace layout
    float* ws   = (float*)d_ws;
    float* cs   = ws;                          // NT_*128 floats (target rows only)
    float* w1t  = cs + (size_t)NT_ * 128;      // 256*128 floats
    __half* hA  = (__half*)(w1t + 256 * 128);  // N*32 halves
    __half* hB  = hA + (size_t)N_ * 32;        // N*32 halves
    int* ebuf   = (int*)(hB + (size_t)N_ * 32);   // KB_*CAP_
    int* pack   = ebuf + (size_t)KB_ * CAP_;   // E
    int* rowptr = pack + E_;                   // N+1
    int* flag   = rowptr + N_ + 1;             // N
    int* cnt    = flag + N_;                   // 1
    int* nlist  = cnt + 1;                     // N
    int* boffs  = nlist + N_;                  // KB_+1
    int* bcur   = boffs + KB_ + 1;             // KB_
    unsigned char* cls = (unsigned char*)(bcur + KB_);  // N bytes

    const int gathBlocks = N_ / 8;             // 12500 (exact)

    // 1. init: cls + zero flag/cnt/bcur + transpose w1
    init_kernel<<<520, 256, 0, stream>>>(x, w1, cls, flag, cnt, bcur, w1t);
    // 2. partition into CAP-strided buckets (global cursors)
    partition_kernel<<<NPBLK, 256, 0, stream>>>(src, dst, etype, bcur, ebuf);
    // 3. dense bases from bucket counts
    bscan_kernel<<<1, 256, 0, stream>>>(bcur, boffs);
    // 4. per-bucket rowptr + dense pack + fused layer 0
    bfinish_kernel<<<KB_, 512, 0, stream>>>(bcur, boffs, ebuf, cls, comp0, V0, loop0, bias0,
                                            rowptr, pack, cs, hA);
    // 5. needed-node set for pruned layer 2
    flagcompact_kernel<<<391, 256, 0, stream>>>(rowptr, pack, flag, cnt, nlist);
    // 6. Layer 1 (full sweep): hA -> hB
    gather_kernel<<<gathBlocks, 256, 0, stream>>>(
        hA, rowptr, pack, comps + 0, Vs + 0, loops + 0, biases + 0, cs, hB, 32);
    // 7. Layer 2 (pruned): hB -> hA
    gatherL_kernel<<<gathBlocks, 256, 0, stream>>>(
        hB, rowptr, pack, comps + 10, Vs + 2048, loops + 1024, biases + 32,
        nlist, cnt, cs, hA, 64);
    // 8. MLP head with fused layer 3 (reads hA)
    mlp_kernel<<<B_, 128, 0, stream>>>(
        hA, rowptr, pack, comps + 20, Vs + 4096, loops + 2048, biases + 64,
        cs, w1t, b1, w2, b2, out);
}

// Round 9
// 172.027 us; speedup vs baseline: 4.9312x; 1.0883x over previous
//
#include <hip/hip_runtime.h>
#include <hip/hip_fp16.h>

// Problem constants (match reference)
constexpr int N_  = 100000;   // nodes
constexpr int E_  = 1600000;  // edges
constexpr int B_  = 2048;     // pairs
constexpr int NT_ = 2 * B_;   // 4096 target nodes (users+items) read by MLP

constexpr int NPB_SHIFT = 9;                    // 512 nodes per bucket
constexpr int NPB = 1 << NPB_SHIFT;
constexpr int KB_ = (N_ + NPB - 1) / NPB;       // 196 buckets
constexpr int CAP_ = 9216;                      // per-bucket capacity (mean 8192, 11 sigma)
constexpr int PCHUNK = 8192;                    // edges per partition block
constexpr int NPBLK = (E_ + PCHUNK - 1) / PCHUNK; // 196 blocks

// ================= init: cls + zero(flag,cnt,bcur) + transpose w1 =================
__global__ __launch_bounds__(256) void init_kernel(
    const float* __restrict__ x, const float* __restrict__ w1,
    unsigned char* __restrict__ cls, int* __restrict__ flag,
    int* __restrict__ cnt, int* __restrict__ bcur, float* __restrict__ w1t)
{
    const int b = blockIdx.x, t = threadIdx.x;
    if (b < 391) {
        const int n = b * 256 + t;
        if (n < N_) {
            const float4 v = *(const float4*)(x + n * 4);
            cls[n] = v.y > 0.5f ? 1 : (v.z > 0.5f ? 2 : (v.w > 0.5f ? 3 : 0));
            flag[n] = 0;
        }
        if (b == 0 && t == 0) *cnt = 0;
    } else if (b < 519) {
        const int idx = (b - 391) * 256 + t;   // < 32768
        const int j = idx >> 8, k = idx & 255;
        w1t[k * 128 + j] = w1[idx];
    } else {
        if (t < KB_) bcur[t] = 0;
    }
}

// ========== partition: edges -> CAP-strided bucket regions (no pre-scan) ==========
// pack word = src(17) | etype(3)<<17 | dloc(9)<<20
__global__ __launch_bounds__(256) void partition_kernel(
    const int* __restrict__ src, const int* __restrict__ dst,
    const int* __restrict__ etype, int* __restrict__ bcur, int* __restrict__ ebuf)
{
    __shared__ int hist[KB_];
    __shared__ int gbase[KB_];
    __shared__ int lcur[KB_];
    const int t = threadIdx.x;
    for (int i = t; i < KB_; i += 256) { hist[i] = 0; lcur[i] = 0; }
    __syncthreads();
    const int e0 = blockIdx.x * PCHUNK;
    const int e1 = min(e0 + PCHUNK, E_);
    for (int i = e0 + t; i < e1; i += 256) atomicAdd(&hist[dst[i] >> NPB_SHIFT], 1);
    __syncthreads();
    for (int i = t; i < KB_; i += 256) if (hist[i]) gbase[i] = atomicAdd(&bcur[i], hist[i]);
    __syncthreads();
    for (int i = e0 + t; i < e1; i += 256) {
        const int d = dst[i];
        const int b = d >> NPB_SHIFT;
        const int lp = atomicAdd(&lcur[b], 1);
        ebuf[(size_t)b * CAP_ + gbase[b] + lp] = src[i] | (etype[i] << 17) | ((d & (NPB - 1)) << 20);
    }
}

// == fused per-bucket: bucket-scan -> hist -> node-scan -> rowptr -> scatter -> L0 ==
// Blocks [0,KB_): CSR + layer 0 for one bucket. Blocks [KB_,KB_+8): needed-set
// build for pruned layer 2 (reads ebuf of buckets 0..7 = all edges with dst<NT_).
__global__ __launch_bounds__(512) void bfinish_kernel(
    const int* __restrict__ bcur, const int* __restrict__ ebuf,
    const unsigned char* __restrict__ cls,
    const float* __restrict__ comp0, const float* __restrict__ V0,
    const float* __restrict__ loop0, const float* __restrict__ bias0,
    int* __restrict__ rowptr, int* __restrict__ pack,
    float* __restrict__ cs, __half* __restrict__ hout,
    int* __restrict__ flag, int* __restrict__ cnt_g, int* __restrict__ nlist)
{
    const int b = blockIdx.x, t = threadIdx.x;
    if (b >= KB_) {
        // ---- needed-set blocks: targets + dedup'd srcs of edges into [0,NT_) ----
        const int tb = b - KB_;                 // 0..7
        const int s0 = tb * CAP_;
        const int s1 = s0 + bcur[tb];
        const int nbase = tb << NPB_SHIFT;      // nodes nbase..nbase+511 (< NT_)
        for (int nn = nbase + t; nn < nbase + NPB; nn += 512)
            nlist[atomicAdd(cnt_g, 1)] = nn;
        for (int i = s0 + t; i < s1; i += 512) {
            const int s = ebuf[i] & 0x1FFFF;
            if (s >= NT_ && atomicExch(&flag[s], 1) == 0)
                nlist[atomicAdd(cnt_g, 1)] = s;
        }
        return;
    }
    __shared__ int cnt[NPB];            // degree hist, later scatter cursors
    __shared__ int sh[NPB];             // scan workspace (bucket scan, then node scan)
    __shared__ unsigned int hist[NPB * 20];  // (rel x cls) histogram per node
    __shared__ float sLoop[128], sV0[256], sBias[32], sCmp[10];
    cnt[t] = 0;
    for (int i = t; i < NPB * 20; i += 512) hist[i] = 0u;
    if (t < 128) sLoop[t] = loop0[t];
    if (t < 256) sV0[t]   = V0[t];
    if (t < 32)  sBias[t] = bias0[t];
    if (t < 10)  sCmp[t]  = comp0[t];
    // ---- folded bscan: exclusive prefix of bcur over KB_ buckets ----
    if (t < 256) sh[t] = (t < KB_) ? bcur[t] : 0;
    __syncthreads();
#pragma unroll
    for (int off = 1; off < 256; off <<= 1) {
        int u = 0;
        if (t < 256 && t >= off) u = sh[t - off];
        __syncthreads();
        if (t < 256) sh[t] += u;
        __syncthreads();
    }
    const int myCnt = bcur[b];
    const int db = sh[b] - myCnt;       // dense base for this bucket
    const int s0 = b * CAP_;
    const int s1 = s0 + myCnt;
    __syncthreads();                    // sh free for reuse
    for (int i = s0 + t; i < s1; i += 512) {
        const int p = ebuf[i];
        const int dloc = p >> 20;
        const int et = (p >> 17) & 7;
        const int c = cls[p & 0x1FFFF];
        atomicAdd(&cnt[dloc], 1);
        atomicAdd(&hist[dloc * 20 + et * 4 + c], 1u);
    }
    __syncthreads();
    const int v = cnt[t];
    sh[t] = v; __syncthreads();
#pragma unroll
    for (int off = 1; off < NPB; off <<= 1) {
        const int u = (t >= off) ? sh[t - off] : 0;
        __syncthreads();
        sh[t] += u;
        __syncthreads();
    }
    const int rp = db + sh[t] - v;      // dense exclusive prefix + bucket base
    const int node = (b << NPB_SHIFT) + t;
    if (node < N_) rowptr[node] = rp;
    cnt[t] = rp;                        // reuse as cursor
    if (b == 0 && t == 0) rowptr[N_] = E_;
    __syncthreads();
    for (int i = s0 + t; i < s1; i += 512) {
        const int p = ebuf[i];
        const int pos = atomicAdd(&cnt[p >> 20], 1);
        pack[pos] = p & 0xFFFFF;        // src | etype<<17
    }
    // ---- layer 0 output for this bucket's nodes (hist is stable) ----
    if (node < N_) {
        float A0[4], A1[4];
#pragma unroll
        for (int j = 0; j < 4; ++j) {
            float a0 = 0.f, a1 = 0.f;
#pragma unroll
            for (int r = 0; r < 5; ++r) {
                const float c = (float)hist[t * 20 + r * 4 + j];
                a0 += c * sCmp[r * 2];
                a1 += c * sCmp[r * 2 + 1];
            }
            A0[j] = a0; A1[j] = a1;
        }
        const int myc = cls[node];
        __half hrow[32];
        const bool wcs = node < NT_;
#pragma unroll 8
        for (int d = 0; d < 32; ++d) {
            float o = sBias[d] + sLoop[myc * 32 + d];
#pragma unroll
            for (int j = 0; j < 4; ++j)
                o += A0[j] * sV0[j * 32 + d] + A1[j] * sV0[128 + j * 32 + d];
            const float r = tanhf(o);
            hrow[d] = __float2half(r);
            if (wcs) cs[node * 128 + d] = r;
        }
        uint4* dst4 = (uint4*)(hout + (size_t)node * 32);
        const uint4* src4 = (const uint4*)hrow;
        dst4[0] = src4[0]; dst4[1] = src4[1]; dst4[2] = src4[2]; dst4[3] = src4[3];
    }
}

// ======================= shared gather body (K = 32) =======================
// 4 lanes per edge; packed fp16 accumulation: per edge 8 x v_pk_fma_f16 with
// splat-coefficient half2 from LDS. Each lane accumulates <=4 edges in fp16,
// converted to f32 before the cross-lane reduce (rounding depth ~4).
__device__ __forceinline__ void acc_chunk(
    const uint4& v, int pq, bool ok, const __half2* __restrict__ cmp2,
    __half2* h0, __half2* h1)
{
    const int tt = (pq >> 17) & 7;
    const __half2 z = __float2half2_rn(0.f);
    const __half2 c0 = ok ? cmp2[tt * 2]     : z;
    const __half2 c1 = ok ? cmp2[tt * 2 + 1] : z;
    const __half2* hp = (const __half2*)&v;
#pragma unroll
    for (int k = 0; k < 4; ++k) {
        h0[k] = __hfma2(c0, hp[k], h0[k]);
        h1[k] = __hfma2(c1, hp[k], h1[k]);
    }
}

__device__ __forceinline__ float gather_body(
    int n, int lane, int g,
    const __half* __restrict__ hin, const int* __restrict__ rowptr,
    const int* __restrict__ pack, const __half2* __restrict__ cmp2,
    const float* __restrict__ V, const float* __restrict__ loopW,
    const float* __restrict__ bias, float (*hs)[96])
{
    hs[g][lane] = __half2float(hin[n * 32 + lane]);
    const int beg = rowptr[n], end = rowptr[n + 1];
    const int sg = lane >> 2;       // edge slot 0..7
    const int c  = lane & 3;        // dim chunk: dims 8c..8c+7
    const int i0 = beg + sg, i1 = i0 + 8, i2 = i0 + 16, i3 = i0 + 24;
    // 4 independent pack loads
    const int p0 = pack[i0 < end ? i0 : beg];
    const int p1 = pack[i1 < end ? i1 : beg];
    const int p2 = pack[i2 < end ? i2 : beg];
    const int p3 = pack[i3 < end ? i3 : beg];
    // 4 h loads, each dependent only on its own pack word
    const uint4 v0 = *(const uint4*)(hin + (size_t)(p0 & 0x1FFFF) * 32 + c * 8);
    const uint4 v1 = *(const uint4*)(hin + (size_t)(p1 & 0x1FFFF) * 32 + c * 8);
    const uint4 v2 = *(const uint4*)(hin + (size_t)(p2 & 0x1FFFF) * 32 + c * 8);
    const uint4 v3 = *(const uint4*)(hin + (size_t)(p3 & 0x1FFFF) * 32 + c * 8);
    __half2 h0[4], h1[4];
    const __half2 z = __float2half2_rn(0.f);
#pragma unroll
    for (int k = 0; k < 4; ++k) { h0[k] = z; h1[k] = z; }
    acc_chunk(v0, p0, i0 < end, cmp2, h0, h1);
    acc_chunk(v1, p1, i1 < end, cmp2, h0, h1);
    acc_chunk(v2, p2, i2 < end, cmp2, h0, h1);
    acc_chunk(v3, p3, i3 < end, cmp2, h0, h1);
    // rare tail: deg > 32
    for (int e0 = beg + 32; e0 < end; e0 += 8) {
        const int e = e0 + sg;
        const bool ok = e < end;
        const int p = pack[ok ? e : beg];
        const uint4 u = *(const uint4*)(hin + (size_t)(p & 0x1FFFF) * 32 + c * 8);
        acc_chunk(u, p, ok, cmp2, h0, h1);
    }
    // convert to f32, then cross-slot reduce
    float a0[8], a1[8];
#pragma unroll
    for (int k = 0; k < 4; ++k) {
        const float2 f0 = __half22float2(h0[k]);
        const float2 f1 = __half22float2(h1[k]);
        a0[2 * k] = f0.x; a0[2 * k + 1] = f0.y;
        a1[2 * k] = f1.x; a1[2 * k + 1] = f1.y;
    }
#pragma unroll
    for (int k = 0; k < 8; ++k) {
        a0[k] += __shfl_xor(a0[k], 4);
        a0[k] += __shfl_xor(a0[k], 8);
        a0[k] += __shfl_xor(a0[k], 16);
        a1[k] += __shfl_xor(a1[k], 4);
        a1[k] += __shfl_xor(a1[k], 8);
        a1[k] += __shfl_xor(a1[k], 16);
    }
    if (lane < 4) {
#pragma unroll
        for (int k = 0; k < 8; ++k) {
            hs[g][32 + c * 8 + k] = a0[k];
            hs[g][64 + c * 8 + k] = a1[k];
        }
    }
    __builtin_amdgcn_wave_barrier();   // 32-lane group is within one wave64
    float o = bias[lane];
#pragma unroll 8
    for (int k = 0; k < 32; ++k) {
        o += hs[g][k] * loopW[k * 32 + lane]
           + hs[g][32 + k] * V[k * 32 + lane]
           + hs[g][64 + k] * V[1024 + k * 32 + lane];
    }
    return tanhf(o);
}

// Full-sweep gather (layer 1): n = blockIdx*8+g, grid exact
__global__ __launch_bounds__(256) void gather_kernel(
    const __half* __restrict__ hin, const int* __restrict__ rowptr,
    const int* __restrict__ pack, const float* __restrict__ comp,
    const float* __restrict__ V, const float* __restrict__ loopW,
    const float* __restrict__ bias,
    float* __restrict__ cs, __half* __restrict__ hout, int out_off)
{
    __shared__ float hs[8][96];
    __shared__ __half2 cmp2[10];
    const int t = threadIdx.x, lane = t & 31, g = t >> 5;
    if (lane < 10) cmp2[lane] = __float2half2_rn(comp[lane]);  // per-wave benign race
    __builtin_amdgcn_wave_barrier();
    const int n = blockIdx.x * 8 + g;
    const float r = gather_body(n, lane, g, hin, rowptr, pack, cmp2, V, loopW, bias, hs);
    if (n < NT_) cs[n * 128 + out_off + lane] = r;
    hout[n * 32 + lane] = __float2half(r);
}

// Pruned gather over compacted node list (barrier-free -> early exit legal)
__global__ __launch_bounds__(256) void gatherL_kernel(
    const __half* __restrict__ hin, const int* __restrict__ rowptr,
    const int* __restrict__ pack, const float* __restrict__ comp,
    const float* __restrict__ V, const float* __restrict__ loopW,
    const float* __restrict__ bias,
    const int* __restrict__ nlist, const int* __restrict__ cnt,
    float* __restrict__ cs, __half* __restrict__ hout, int out_off)
{
    __shared__ float hs[8][96];
    __shared__ __half2 cmp2[10];
    const int t = threadIdx.x, lane = t & 31, g = t >> 5;
    if (lane < 10) cmp2[lane] = __float2half2_rn(comp[lane]);
    __builtin_amdgcn_wave_barrier();
    const int idx = blockIdx.x * 8 + g;
    if (idx >= *cnt) return;                 // no block barriers below: safe
    const int n = nlist[idx];
    const float r = gather_body(n, lane, g, hin, rowptr, pack, cmp2, V, loopW, bias, hs);
    if (n < NT_) cs[n * 128 + out_off + lane] = r;
    hout[n * 32 + lane] = __float2half(r);
}

// ================= MLP head with fused layer-3 gather (targets only) =============
// wave 0 (threads 0..63): gather layer-3 rows for nodes p and B_+p into feat[96..127].
// wave 1 (threads 64..127): load cs slots 0..95 for both nodes.
__global__ __launch_bounds__(128) void mlp_kernel(
    const __half* __restrict__ hin, const int* __restrict__ rowptr,
    const int* __restrict__ pack, const float* __restrict__ comp,
    const float* __restrict__ V, const float* __restrict__ loopW,
    const float* __restrict__ bias,
    const float* __restrict__ cs, const float* __restrict__ w1t,
    const float* __restrict__ b1, const float* __restrict__ w2,
    const float* __restrict__ b2, float* __restrict__ out)
{
    __shared__ float feat[256];
    __shared__ float hs[2][96];
    __shared__ __half2 cmp2[10];
    __shared__ float part[2];
    const int p = blockIdx.x, t = threadIdx.x;
    if (t < 10) cmp2[t] = __float2half2_rn(comp[t]);   // wave 0, before its gather
    if (t < 64) {
        const int g = t >> 5, lane = t & 31;
        const int n = g ? (B_ + p) : p;
        const float r = gather_body(n, lane, g, hin, rowptr, pack, cmp2, V, loopW, bias, hs);
        feat[g * 128 + 96 + lane] = r;
    } else {
        const int i = t - 64;                // 0..63
        for (int j = i; j < 96; j += 64) {
            feat[j]       = cs[p * 128 + j];
            feat[128 + j] = cs[(B_ + p) * 128 + j];
        }
    }
    __syncthreads();
    float acc = b1[t];
#pragma unroll 8
    for (int k = 0; k < 256; ++k) acc += feat[k] * w1t[k * 128 + t];
    const float hid = acc > 0.f ? acc : 0.f;
    float v = w2[t] * hid;
#pragma unroll
    for (int off = 32; off > 0; off >>= 1) v += __shfl_down(v, off, 64);
    if ((t & 63) == 0) part[t >> 6] = v;
    __syncthreads();
    if (t == 0) out[p] = part[0] + part[1] + b2[0];
}

extern "C" void kernel_launch(void* const* d_in, const int* in_sizes, int n_in,
                              void* d_out, int out_size, void* d_ws, size_t ws_size,
                              hipStream_t stream) {
    const float* x      = (const float*)d_in[0];
    const int*   src    = (const int*)d_in[1];
    const int*   dst    = (const int*)d_in[2];
    const int*   etype  = (const int*)d_in[3];
    const float* V0     = (const float*)d_in[4];
    const float* comp0  = (const float*)d_in[5];
    const float* loop0  = (const float*)d_in[6];
    const float* bias0  = (const float*)d_in[7];
    const float* Vs     = (const float*)d_in[8];    // [3,2,32,32]
    const float* comps  = (const float*)d_in[9];    // [3,5,2]
    const float* loops  = (const float*)d_in[10];   // [3,32,32]
    const float* biases = (const float*)d_in[11];   // [3,32]
    const float* w1     = (const float*)d_in[12];   // [128,256]
    const float* b1     = (const float*)d_in[13];
    const float* w2     = (const float*)d_in[14];   // [1,128]
    const float* b2     = (const float*)d_in[15];
    float* out = (float*)d_out;

    // Workspace layout
    float* ws   = (float*)d_ws;
    float* cs   = ws;                          // NT_*128 floats (target rows only)
    float* w1t  = cs + (size_t)NT_ * 128;      // 256*128 floats
    __half* hA  = (__half*)(w1t + 256 * 128);  // N*32 halves
    __half* hB  = hA + (size_t)N_ * 32;        // N*32 halves
    int* ebuf   = (int*)(hB + (size_t)N_ * 32);   // KB_*CAP_
    int* pack   = ebuf + (size_t)KB_ * CAP_;   // E
    int* rowptr = pack + E_;                   // N+1
    int* flag   = rowptr + N_ + 1;             // N
    int* cnt    = flag + N_;                   // 1
    int* nlist  = cnt + 1;                     // N
    int* bcur   = nlist + N_;                  // KB_
    unsigned char* cls = (unsigned char*)(bcur + KB_);  // N bytes

    const int gathBlocks = N_ / 8;             // 12500 (exact)

    // 1. init: cls + zero flag/cnt/bcur + transpose w1
    init_kernel<<<520, 256, 0, stream>>>(x, w1, cls, flag, cnt, bcur, w1t);
    // 2. partition into CAP-strided buckets (global cursors)
    partition_kernel<<<NPBLK, 256, 0, stream>>>(src, dst, etype, bcur, ebuf);
    // 3. per-bucket: folded bscan + rowptr + dense pack + fused layer 0,
    //    plus 8 extra blocks building the pruned-layer needed set
    bfinish_kernel<<<KB_ + 8, 512, 0, stream>>>(bcur, ebuf, cls, comp0, V0, loop0, bias0,
                                                rowptr, pack, cs, hA, flag, cnt, nlist);
    // 4. Layer 1 (full sweep): hA -> hB
    gather_kernel<<<gathBlocks, 256, 0, stream>>>(
        hA, rowptr, pack, comps + 0, Vs + 0, loops + 0, biases + 0, cs, hB, 32);
    // 5. Layer 2 (pruned): hB -> hA
    gatherL_kernel<<<gathBlocks, 256, 0, stream>>>(
        hB, rowptr, pack, comps + 10, Vs + 2048, loops + 1024, biases + 32,
        nlist, cnt, cs, hA, 64);
    // 6. MLP head with fused layer 3 (reads hA)
    mlp_kernel<<<B_, 128, 0, stream>>>(
        hA, rowptr, pack, comps + 20, Vs + 4096, loops + 2048, biases + 64,
        cs, w1t, b1, w2, b2, out);
}